// Round 1
// baseline (2274.510 us; speedup 1.0000x reference)
//
#include <hip/hip_runtime.h>
#include <math.h>

#define N_ENT  15000
#define N_RELC 237
#define R2C    474
#define HIDC   128
#define NB     128       // padded unique count B = BATCH*NEG
#define EBASE  200000
#define E2     400000
#define EPSV   1e-10f

// ---------------------------------------------------------------------------
// Prep: negative_sample_to_tail + unique(sort+dedup) + inverse indices.
// Single block, 128 threads.
// ---------------------------------------------------------------------------
__global__ void prep_kernel(const int* __restrict__ h_index,
                            const int* __restrict__ t_index,
                            const int* __restrict__ r_index,
                            int* __restrict__ h_set, int* __restrict__ r_set,
                            int* __restrict__ invp, int* __restrict__ t_flat) {
    __shared__ int s[128];
    __shared__ int eq[128];
    __shared__ int isneg[8];
    __shared__ int uniq[128];
    __shared__ int flag[128];
    __shared__ int pos[128];
    __shared__ int Ucnt;
    int j = threadIdx.x;
    int b = j >> 4;                     // batch row (16 negs per row)
    int h = h_index[j], t = t_index[j], r = r_index[j];

    eq[j] = (h == h_index[b * 16]) ? 1 : 0;
    __syncthreads();
    if ((j & 15) == 0) {
        int a = 1;
        for (int q = 0; q < 16; q++) a &= eq[b * 16 + q];
        isneg[b] = a;
    }
    __syncthreads();

    int hi, ti, ri;
    if (isneg[b]) { hi = h; ti = t; ri = r; }
    else          { hi = t; ti = h; ri = r + N_RELC; }
    t_flat[j] = ti;
    int hrv = hi * R2C + ri;
    s[j] = hrv;
    __syncthreads();

    // odd-even transposition sort, 128 phases (n phases suffice for n elems)
    for (int p = 0; p < 128; p++) {
        if (j < 64) {
            int idx = 2 * j + (p & 1);
            if (idx + 1 < 128) {
                int a = s[idx], c = s[idx + 1];
                if (a > c) { s[idx] = c; s[idx + 1] = a; }
            }
        }
        __syncthreads();
    }

    flag[j] = (j == 0) ? 1 : ((s[j] != s[j - 1]) ? 1 : 0);
    __syncthreads();
    if (j == 0) {
        int c = 0;
        for (int q = 0; q < 128; q++) {
            if (flag[q]) { pos[q] = c; c++; } else pos[q] = -1;
        }
        Ucnt = c;
    }
    __syncthreads();
    uniq[j] = 0;                       // fill_value = 0 padding
    __syncthreads();
    if (flag[j]) uniq[pos[j]] = s[j];
    __syncthreads();

    h_set[j] = uniq[j] / R2C;
    r_set[j] = uniq[j] % R2C;

    int U = Ucnt;
    int f = 0;
    for (int q = 0; q < U; q++) { if (uniq[q] == hrv) { f = q; break; } }
    invp[j] = f;
}

// ---------------------------------------------------------------------------
// One LSTM step. grid = 128 (one block per b), block = 128 threads.
// ---------------------------------------------------------------------------
__global__ void lstm_step_kernel(const float* __restrict__ query_emb,
                                 const int* __restrict__ r_set, int step,
                                 const float* __restrict__ w_ih,
                                 const float* __restrict__ w_hh,
                                 const float* __restrict__ b_ih,
                                 const float* __restrict__ b_hh,
                                 float* __restrict__ hbuf, float* __restrict__ cbuf,
                                 float* __restrict__ hidden) {
    int b = blockIdx.x, tid = threadIdx.x;
    __shared__ float x[128], hp[128], g[512];
    int qrow = (step < 2) ? r_set[b] : R2C;     // last step uses end token
    x[tid]  = query_emb[qrow * 128 + tid];
    hp[tid] = (step == 0) ? 0.f : hbuf[b * 128 + tid];
    __syncthreads();
    for (int q = 0; q < 4; q++) {
        int gi = q * 128 + tid;
        float acc = b_ih[gi] + b_hh[gi];
        const float* wi = w_ih + gi * 128;
        const float* wh = w_hh + gi * 128;
        #pragma unroll 8
        for (int d = 0; d < 128; d++) acc += x[d] * wi[d] + hp[d] * wh[d];
        g[gi] = acc;
    }
    __syncthreads();
    float ig = g[tid], fg = g[128 + tid], gg = g[256 + tid], og = g[384 + tid];
    float c = (step == 0) ? 0.f : cbuf[b * 128 + tid];
    float si = 1.f / (1.f + expf(-ig));
    float sf = 1.f / (1.f + expf(-fg));
    float so = 1.f / (1.f + expf(-og));
    c = sf * c + si * tanhf(gg);
    float hh = so * tanhf(c);
    cbuf[b * 128 + tid] = c;
    hbuf[b * 128 + tid] = hh;
    hidden[(step * 128 + b) * 128 + tid] = hh;
}

// ---------------------------------------------------------------------------
// Attention over hidden[0..step]. grid = 128 (b), block = 128.
// ---------------------------------------------------------------------------
__global__ void attn_kernel(const float* __restrict__ hidden, int step,
                            float* __restrict__ attn) {
    int b = blockIdx.x, tid = threadIdx.x;
    __shared__ float red[128];
    float k = hidden[(step * 128 + b) * 128 + tid];
    float sc[3];
    for (int t = 0; t <= step; t++) {
        float v = k * hidden[(t * 128 + b) * 128 + tid];
        red[tid] = v; __syncthreads();
        for (int s2 = 64; s2 > 0; s2 >>= 1) {
            if (tid < s2) red[tid] += red[tid + s2];
            __syncthreads();
        }
        sc[t] = red[0];
        __syncthreads();
    }
    if (tid == 0) {
        float m = sc[0];
        for (int t = 1; t <= step; t++) m = fmaxf(m, sc[t]);
        float s = 0.f;
        for (int t = 0; t <= step; t++) { sc[t] = expf(sc[t] - m); s += sc[t]; }
        for (int t = 0; t <= step; t++) attn[b * 4 + t] = sc[t] / s;
    }
}

// ---------------------------------------------------------------------------
// Relation weights: wT[r][b] = softmax_r(k_b . weight_w[r] + weight_b[r]).
// grid = 128 (b), block = 256.
// ---------------------------------------------------------------------------
__global__ void relw_kernel(const float* __restrict__ hidden, int step,
                            const float* __restrict__ weight_w,
                            const float* __restrict__ weight_b,
                            float* __restrict__ wT) {
    int b = blockIdx.x, tid = threadIdx.x;
    __shared__ float k[128];
    __shared__ float logit[R2C];
    __shared__ float red[256];
    if (tid < 128) k[tid] = hidden[(step * 128 + b) * 128 + tid];
    __syncthreads();
    for (int r = tid; r < R2C; r += 256) {
        const float* wr = weight_w + r * 128;
        float acc = weight_b[r];
        #pragma unroll 8
        for (int d = 0; d < 128; d++) acc += k[d] * wr[d];
        logit[r] = acc;
    }
    __syncthreads();
    float m = -1e30f;
    for (int r = tid; r < R2C; r += 256) m = fmaxf(m, logit[r]);
    red[tid] = m; __syncthreads();
    for (int s2 = 128; s2 > 0; s2 >>= 1) {
        if (tid < s2) red[tid] = fmaxf(red[tid], red[tid + s2]);
        __syncthreads();
    }
    m = red[0]; __syncthreads();
    float s = 0.f;
    for (int r = tid; r < R2C; r += 256) s += expf(logit[r] - m);
    red[tid] = s; __syncthreads();
    for (int s2 = 128; s2 > 0; s2 >>= 1) {
        if (tid < s2) red[tid] += red[tid + s2];
        __syncthreads();
    }
    s = red[0];
    float invs = 1.f / s;
    for (int r = tid; r < R2C; r += 256) wT[r * 128 + b] = expf(logit[r] - m) * invs;
}

// ---------------------------------------------------------------------------
// inp[n][b] = attn[b][0]*(n==h_set[b]) + sum_{t>=1} attn[b][t]*out_{t-1}[n][b]
// grid = 2048 blocks (row-stride), block = 128 (thread = b).
// ---------------------------------------------------------------------------
__global__ void inp_kernel(const float* __restrict__ o1, const float* __restrict__ o2,
                           int step, const float* __restrict__ attn,
                           const int* __restrict__ h_set, float* __restrict__ inp) {
    int b = threadIdx.x;
    float a0 = attn[b * 4 + 0];
    float a1 = (step >= 1) ? attn[b * 4 + 1] : 0.f;
    float a2 = (step >= 2) ? attn[b * 4 + 2] : 0.f;
    int hs = h_set[b];
    for (int n = blockIdx.x; n < N_ENT; n += gridDim.x) {
        float v = (n == hs) ? a0 : 0.f;
        if (step >= 1) v += a1 * o1[n * 128 + b];
        if (step >= 2) v += a2 * o2[n * 128 + b];
        inp[n * 128 + b] = v;
    }
}

// ---------------------------------------------------------------------------
// Scatter: out[node_out[e]][b] += inp[node_in[e]][b] * wT[rel[e]][b] * ew[e]
// 32 threads per edge (float4 over 128 cols), 8 edges per 256-thread block.
// ---------------------------------------------------------------------------
__global__ void scatter_kernel(const int* __restrict__ src, const int* __restrict__ dst,
                               const int* __restrict__ rel, const float* __restrict__ ew,
                               const float* __restrict__ inp, const float* __restrict__ wT,
                               float* __restrict__ out) {
    int gid = blockIdx.x * 256 + threadIdx.x;
    int e = gid >> 5;
    int c = gid & 31;
    if (e >= E2) return;
    int ni, no, r;
    if (e < EBASE) { ni = src[e]; no = dst[e]; r = rel[e]; }
    else { int e2 = e - EBASE; ni = dst[e2]; no = src[e2]; r = rel[e2] + N_RELC; }
    float w = ew[e];
    float4 a  = ((const float4*)(inp + ni * 128))[c];
    float4 ww = ((const float4*)(wT + r * 128))[c];
    float* ob = out + no * 128 + c * 4;
    atomicAdd(ob + 0, a.x * ww.x * w);
    atomicAdd(ob + 1, a.y * ww.y * w);
    atomicAdd(ob + 2, a.z * ww.z * w);
    atomicAdd(ob + 3, a.w * ww.w * w);
}

// ---------------------------------------------------------------------------
// Column sums S[b] = sum_n out[n][b]. grid = 256, block = 128 (thread = b).
// ---------------------------------------------------------------------------
__global__ void colsum_kernel(const float* __restrict__ out, float* __restrict__ S) {
    int b = threadIdx.x;
    float acc = 0.f;
    for (int n = blockIdx.x; n < N_ENT; n += gridDim.x) acc += out[n * 128 + b];
    atomicAdd(&S[b], acc);
}

// out[n][b] /= max(S[b], EPS)
__global__ void norm_kernel(float* __restrict__ out, const float* __restrict__ S) {
    int idx = blockIdx.x * 256 + threadIdx.x;
    if (idx >= N_ENT * 128) return;
    int b = idx & 127;
    out[idx] = out[idx] / fmaxf(S[b], EPSV);
}

// score[j] = out3[t_flat[j]][inv[j]] * lin_w + lin_b. 1 block, 128 threads.
__global__ void score_kernel(const float* __restrict__ out3,
                             const int* __restrict__ t_flat, const int* __restrict__ invp,
                             const float* __restrict__ lin_w, const float* __restrict__ lin_b,
                             float* __restrict__ d_out) {
    int j = threadIdx.x;
    d_out[j] = out3[t_flat[j] * 128 + invp[j]] * lin_w[0] + lin_b[0];
}

// ---------------------------------------------------------------------------
extern "C" void kernel_launch(void* const* d_in, const int* in_sizes, int n_in,
                              void* d_out, int out_size, void* d_ws, size_t ws_size,
                              hipStream_t stream) {
    const float* query_emb  = (const float*)d_in[0];
    const float* w_ih       = (const float*)d_in[1];
    const float* w_hh       = (const float*)d_in[2];
    const float* b_ih       = (const float*)d_in[3];
    const float* b_hh       = (const float*)d_in[4];
    const float* weight_w   = (const float*)d_in[5];
    const float* weight_b   = (const float*)d_in[6];
    const float* lin_w      = (const float*)d_in[7];
    const float* lin_b      = (const float*)d_in[8];
    const float* edge_weight= (const float*)d_in[9];
    const int*   h_index    = (const int*)d_in[10];
    const int*   t_index    = (const int*)d_in[11];
    const int*   r_index    = (const int*)d_in[12];
    const int*   src        = (const int*)d_in[13];
    const int*   dst        = (const int*)d_in[14];
    const int*   rel        = (const int*)d_in[15];
    float* out = (float*)d_out;

    char* ws = (char*)d_ws;
    size_t off = 0;
    auto alloc = [&](size_t bytes) -> void* {
        void* p = ws + off;
        off = (off + bytes + 255) & ~(size_t)255;
        return p;
    };
    float* hidden = (float*)alloc(3 * 128 * 128 * sizeof(float));
    float* hbuf   = (float*)alloc(128 * 128 * sizeof(float));
    float* cbuf   = (float*)alloc(128 * 128 * sizeof(float));
    float* attn   = (float*)alloc(128 * 4 * sizeof(float));
    float* wT     = (float*)alloc(R2C * 128 * sizeof(float));
    float* S      = (float*)alloc(128 * sizeof(float));
    int*   h_set  = (int*)alloc(128 * sizeof(int));
    int*   r_set  = (int*)alloc(128 * sizeof(int));
    int*   invp   = (int*)alloc(128 * sizeof(int));
    int*   t_flat = (int*)alloc(128 * sizeof(int));
    float* inp    = (float*)alloc((size_t)N_ENT * 128 * sizeof(float));
    float* outs[3];
    for (int i = 0; i < 3; i++) outs[i] = (float*)alloc((size_t)N_ENT * 128 * sizeof(float));

    prep_kernel<<<1, 128, 0, stream>>>(h_index, t_index, r_index, h_set, r_set, invp, t_flat);

    for (int step = 0; step < 3; step++) {
        lstm_step_kernel<<<128, 128, 0, stream>>>(query_emb, r_set, step,
                                                  w_ih, w_hh, b_ih, b_hh,
                                                  hbuf, cbuf, hidden);
    }

    for (int i = 0; i < 3; i++) {
        attn_kernel<<<128, 128, 0, stream>>>(hidden, i, attn);
        relw_kernel<<<128, 256, 0, stream>>>(hidden, i, weight_w, weight_b, wT);
        inp_kernel<<<2048, 128, 0, stream>>>(outs[0], outs[1], i, attn, h_set, inp);
        hipMemsetAsync(outs[i], 0, (size_t)N_ENT * 128 * sizeof(float), stream);
        hipMemsetAsync(S, 0, 128 * sizeof(float), stream);
        scatter_kernel<<<(E2 * 32 + 255) / 256, 256, 0, stream>>>(src, dst, rel, edge_weight,
                                                                  inp, wT, outs[i]);
        colsum_kernel<<<256, 128, 0, stream>>>(outs[i], S);
        norm_kernel<<<(N_ENT * 128 + 255) / 256, 256, 0, stream>>>(outs[i], S);
    }

    score_kernel<<<1, 128, 0, stream>>>(outs[2], t_flat, invp, lin_w, lin_b, out);
}

// Round 2
// 457.928 us; speedup vs baseline: 4.9670x; 4.9670x over previous
//
#include <hip/hip_runtime.h>
#include <math.h>

#define N_ENT  15000
#define N_RELC 237
#define R2C    474
#define HIDC   128
#define NB     128       // padded unique count B = BATCH*NEG
#define EBASE  200000
#define E2     400000
#define EPSV   1e-10f

// ---------------------------------------------------------------------------
// Prep: negative_sample_to_tail + unique(sort+dedup) + inverse indices.
// Single block, 128 threads.
// ---------------------------------------------------------------------------
__global__ void prep_kernel(const int* __restrict__ h_index,
                            const int* __restrict__ t_index,
                            const int* __restrict__ r_index,
                            int* __restrict__ h_set, int* __restrict__ r_set,
                            int* __restrict__ invp, int* __restrict__ t_flat) {
    __shared__ int s[128];
    __shared__ int eq[128];
    __shared__ int isneg[8];
    __shared__ int uniq[128];
    __shared__ int flag[128];
    __shared__ int pos[128];
    __shared__ int Ucnt;
    int j = threadIdx.x;
    int b = j >> 4;                     // batch row (16 negs per row)
    int h = h_index[j], t = t_index[j], r = r_index[j];

    eq[j] = (h == h_index[b * 16]) ? 1 : 0;
    __syncthreads();
    if ((j & 15) == 0) {
        int a = 1;
        for (int q = 0; q < 16; q++) a &= eq[b * 16 + q];
        isneg[b] = a;
    }
    __syncthreads();

    int hi, ti, ri;
    if (isneg[b]) { hi = h; ti = t; ri = r; }
    else          { hi = t; ti = h; ri = r + N_RELC; }
    t_flat[j] = ti;
    int hrv = hi * R2C + ri;
    s[j] = hrv;
    __syncthreads();

    // odd-even transposition sort, 128 phases
    for (int p = 0; p < 128; p++) {
        if (j < 64) {
            int idx = 2 * j + (p & 1);
            if (idx + 1 < 128) {
                int a = s[idx], c = s[idx + 1];
                if (a > c) { s[idx] = c; s[idx + 1] = a; }
            }
        }
        __syncthreads();
    }

    flag[j] = (j == 0) ? 1 : ((s[j] != s[j - 1]) ? 1 : 0);
    __syncthreads();
    if (j == 0) {
        int c = 0;
        for (int q = 0; q < 128; q++) {
            if (flag[q]) { pos[q] = c; c++; } else pos[q] = -1;
        }
        Ucnt = c;
    }
    __syncthreads();
    uniq[j] = 0;                       // fill_value = 0 padding
    __syncthreads();
    if (flag[j]) uniq[pos[j]] = s[j];
    __syncthreads();

    h_set[j] = uniq[j] / R2C;
    r_set[j] = uniq[j] % R2C;

    int U = Ucnt;
    int f = 0;
    for (int q = 0; q < U; q++) { if (uniq[q] == hrv) { f = q; break; } }
    invp[j] = f;
}

// ---------------------------------------------------------------------------
// Edge sort by destination: histogram -> scan -> fill.
// ---------------------------------------------------------------------------
__global__ void hist_kernel(const int* __restrict__ src, const int* __restrict__ dst,
                            int* __restrict__ deg) {
    int e = blockIdx.x * 256 + threadIdx.x;
    if (e >= E2) return;
    int no = (e < EBASE) ? dst[e] : src[e - EBASE];
    atomicAdd(&deg[no], 1);
}

// single block, 1024 threads: exclusive scan of deg[0..N_ENT) -> off
__global__ void scan_kernel(const int* __restrict__ deg, int* __restrict__ off) {
    __shared__ int ps[1024];
    int t = threadIdx.x;
    const int CH = 15;                  // 1024*15 >= 15000
    int base = t * CH;
    int loc = 0;
    for (int q = 0; q < CH; q++) {
        int idx = base + q;
        if (idx < N_ENT) loc += deg[idx];
    }
    ps[t] = loc;
    __syncthreads();
    for (int d = 1; d < 1024; d <<= 1) {
        int v = (t >= d) ? ps[t - d] : 0;
        __syncthreads();
        ps[t] += v;
        __syncthreads();
    }
    int run = ps[t] - loc;              // exclusive base for this chunk
    for (int q = 0; q < CH; q++) {
        int idx = base + q;
        if (idx < N_ENT) { off[idx] = run; run += deg[idx]; }
    }
    if (t == 1023) off[N_ENT] = ps[1023];
}

// scatter edges into dst-sorted order; record = {(ni<<9)|r, bits(w)}
__global__ void fill_kernel(const int* __restrict__ src, const int* __restrict__ dst,
                            const int* __restrict__ rel, const float* __restrict__ ew,
                            const int* __restrict__ off, int* __restrict__ cursor,
                            int2* __restrict__ edata) {
    int e = blockIdx.x * 256 + threadIdx.x;
    if (e >= E2) return;
    int ni, no, r;
    if (e < EBASE) { ni = src[e]; no = dst[e]; r = rel[e]; }
    else { int e2 = e - EBASE; ni = dst[e2]; no = src[e2]; r = rel[e2] + N_RELC; }
    int pos = off[no] + atomicAdd(&cursor[no], 1);
    edata[pos] = make_int2((ni << 9) | r, __float_as_int(ew[e]));
}

// ---------------------------------------------------------------------------
// One LSTM step. grid = 128 (one block per b), block = 128 threads.
// ---------------------------------------------------------------------------
__global__ void lstm_step_kernel(const float* __restrict__ query_emb,
                                 const int* __restrict__ r_set, int step,
                                 const float* __restrict__ w_ih,
                                 const float* __restrict__ w_hh,
                                 const float* __restrict__ b_ih,
                                 const float* __restrict__ b_hh,
                                 float* __restrict__ hbuf, float* __restrict__ cbuf,
                                 float* __restrict__ hidden) {
    int b = blockIdx.x, tid = threadIdx.x;
    __shared__ float x[128], hp[128], g[512];
    int qrow = (step < 2) ? r_set[b] : R2C;     // last step uses end token
    x[tid]  = query_emb[qrow * 128 + tid];
    hp[tid] = (step == 0) ? 0.f : hbuf[b * 128 + tid];
    __syncthreads();
    for (int q = 0; q < 4; q++) {
        int gi = q * 128 + tid;
        float acc = b_ih[gi] + b_hh[gi];
        const float* wi = w_ih + gi * 128;
        const float* wh = w_hh + gi * 128;
        #pragma unroll 8
        for (int d = 0; d < 128; d++) acc += x[d] * wi[d] + hp[d] * wh[d];
        g[gi] = acc;
    }
    __syncthreads();
    float ig = g[tid], fg = g[128 + tid], gg = g[256 + tid], og = g[384 + tid];
    float c = (step == 0) ? 0.f : cbuf[b * 128 + tid];
    float si = 1.f / (1.f + expf(-ig));
    float sf = 1.f / (1.f + expf(-fg));
    float so = 1.f / (1.f + expf(-og));
    c = sf * c + si * tanhf(gg);
    float hh = so * tanhf(c);
    cbuf[b * 128 + tid] = c;
    hbuf[b * 128 + tid] = hh;
    hidden[(step * 128 + b) * 128 + tid] = hh;
}

// ---------------------------------------------------------------------------
// Attention over hidden[0..step]. grid = 128 (b), block = 128.
// ---------------------------------------------------------------------------
__global__ void attn_kernel(const float* __restrict__ hidden, int step,
                            float* __restrict__ attn) {
    int b = blockIdx.x, tid = threadIdx.x;
    __shared__ float red[128];
    float k = hidden[(step * 128 + b) * 128 + tid];
    float sc[3];
    for (int t = 0; t <= step; t++) {
        float v = k * hidden[(t * 128 + b) * 128 + tid];
        red[tid] = v; __syncthreads();
        for (int s2 = 64; s2 > 0; s2 >>= 1) {
            if (tid < s2) red[tid] += red[tid + s2];
            __syncthreads();
        }
        sc[t] = red[0];
        __syncthreads();
    }
    if (tid == 0) {
        float m = sc[0];
        for (int t = 1; t <= step; t++) m = fmaxf(m, sc[t]);
        float s = 0.f;
        for (int t = 0; t <= step; t++) { sc[t] = expf(sc[t] - m); s += sc[t]; }
        for (int t = 0; t <= step; t++) attn[b * 4 + t] = sc[t] / s;
    }
}

// ---------------------------------------------------------------------------
// Relation weights: wT[r][b] = softmax_r(k_b . weight_w[r] + weight_b[r]).
// grid = 128 (b), block = 256.
// ---------------------------------------------------------------------------
__global__ void relw_kernel(const float* __restrict__ hidden, int step,
                            const float* __restrict__ weight_w,
                            const float* __restrict__ weight_b,
                            float* __restrict__ wT) {
    int b = blockIdx.x, tid = threadIdx.x;
    __shared__ float k[128];
    __shared__ float logit[R2C];
    __shared__ float red[256];
    if (tid < 128) k[tid] = hidden[(step * 128 + b) * 128 + tid];
    __syncthreads();
    for (int r = tid; r < R2C; r += 256) {
        const float* wr = weight_w + r * 128;
        float acc = weight_b[r];
        #pragma unroll 8
        for (int d = 0; d < 128; d++) acc += k[d] * wr[d];
        logit[r] = acc;
    }
    __syncthreads();
    float m = -1e30f;
    for (int r = tid; r < R2C; r += 256) m = fmaxf(m, logit[r]);
    red[tid] = m; __syncthreads();
    for (int s2 = 128; s2 > 0; s2 >>= 1) {
        if (tid < s2) red[tid] = fmaxf(red[tid], red[tid + s2]);
        __syncthreads();
    }
    m = red[0]; __syncthreads();
    float s = 0.f;
    for (int r = tid; r < R2C; r += 256) s += expf(logit[r] - m);
    red[tid] = s; __syncthreads();
    for (int s2 = 128; s2 > 0; s2 >>= 1) {
        if (tid < s2) red[tid] += red[tid + s2];
        __syncthreads();
    }
    s = red[0];
    float invs = 1.f / s;
    for (int r = tid; r < R2C; r += 256) wT[r * 128 + b] = expf(logit[r] - m) * invs;
}

// ---------------------------------------------------------------------------
// inp[n][b] = attn[b][0]*(n==h_set[b]) + sum_{t>=1} attn[b][t]*out_{t-1}[n][b]
// ---------------------------------------------------------------------------
__global__ void inp_kernel(const float* __restrict__ o1, const float* __restrict__ o2,
                           int step, const float* __restrict__ attn,
                           const int* __restrict__ h_set, float* __restrict__ inp) {
    int b = threadIdx.x;
    float a0 = attn[b * 4 + 0];
    float a1 = (step >= 1) ? attn[b * 4 + 1] : 0.f;
    float a2 = (step >= 2) ? attn[b * 4 + 2] : 0.f;
    int hs = h_set[b];
    for (int n = blockIdx.x; n < N_ENT; n += gridDim.x) {
        float v = (n == hs) ? a0 : 0.f;
        if (step >= 1) v += a1 * o1[n * 128 + b];
        if (step >= 2) v += a2 * o2[n * 128 + b];
        inp[n * 128 + b] = v;
    }
}

// ---------------------------------------------------------------------------
// Gather: out[n][b] = sum over incoming edges of inp[ni][b]*wT[r][b]*w.
// One wave (64 lanes) per node, lane = 2 columns (float2). Block 256 = 4 nodes.
// ---------------------------------------------------------------------------
__global__ void gather_kernel(const int2* __restrict__ edata,
                              const int* __restrict__ off,
                              const float* __restrict__ inp,
                              const float* __restrict__ wT,
                              float* __restrict__ out) {
    int wid = threadIdx.x >> 6;
    int lane = threadIdx.x & 63;
    int n = blockIdx.x * 4 + wid;
    if (n >= N_ENT) return;
    int e0 = off[n], e1 = off[n + 1];
    int c = lane * 2;
    float accx = 0.f, accy = 0.f;
    for (int e = e0; e < e1; e++) {
        int2 ed = edata[e];
        int ni = ed.x >> 9;
        int r  = ed.x & 511;
        float w = __int_as_float(ed.y);
        float2 a  = *(const float2*)(inp + ni * 128 + c);
        float2 ww = *(const float2*)(wT + r * 128 + c);
        accx += a.x * ww.x * w;
        accy += a.y * ww.y * w;
    }
    float2 res = make_float2(accx, accy);
    *(float2*)(out + n * 128 + c) = res;
}

// ---------------------------------------------------------------------------
// Column sums S[b] = sum_n out[n][b]. grid = 256, block = 128 (thread = b).
// ---------------------------------------------------------------------------
__global__ void colsum_kernel(const float* __restrict__ out, float* __restrict__ S) {
    int b = threadIdx.x;
    float acc = 0.f;
    for (int n = blockIdx.x; n < N_ENT; n += gridDim.x) acc += out[n * 128 + b];
    atomicAdd(&S[b], acc);
}

// out[n][b] /= max(S[b], EPS)
__global__ void norm_kernel(float* __restrict__ out, const float* __restrict__ S) {
    int idx = blockIdx.x * 256 + threadIdx.x;
    if (idx >= N_ENT * 128) return;
    int b = idx & 127;
    out[idx] = out[idx] / fmaxf(S[b], EPSV);
}

// score[j] = out3[t_flat[j]][inv[j]] * lin_w + lin_b. 1 block, 128 threads.
__global__ void score_kernel(const float* __restrict__ out3,
                             const int* __restrict__ t_flat, const int* __restrict__ invp,
                             const float* __restrict__ lin_w, const float* __restrict__ lin_b,
                             float* __restrict__ d_out) {
    int j = threadIdx.x;
    d_out[j] = out3[t_flat[j] * 128 + invp[j]] * lin_w[0] + lin_b[0];
}

// ---------------------------------------------------------------------------
extern "C" void kernel_launch(void* const* d_in, const int* in_sizes, int n_in,
                              void* d_out, int out_size, void* d_ws, size_t ws_size,
                              hipStream_t stream) {
    const float* query_emb  = (const float*)d_in[0];
    const float* w_ih       = (const float*)d_in[1];
    const float* w_hh       = (const float*)d_in[2];
    const float* b_ih       = (const float*)d_in[3];
    const float* b_hh       = (const float*)d_in[4];
    const float* weight_w   = (const float*)d_in[5];
    const float* weight_b   = (const float*)d_in[6];
    const float* lin_w      = (const float*)d_in[7];
    const float* lin_b      = (const float*)d_in[8];
    const float* edge_weight= (const float*)d_in[9];
    const int*   h_index    = (const int*)d_in[10];
    const int*   t_index    = (const int*)d_in[11];
    const int*   r_index    = (const int*)d_in[12];
    const int*   src        = (const int*)d_in[13];
    const int*   dst        = (const int*)d_in[14];
    const int*   rel        = (const int*)d_in[15];
    float* out = (float*)d_out;

    char* ws = (char*)d_ws;
    size_t off_b = 0;
    auto alloc = [&](size_t bytes) -> void* {
        void* p = ws + off_b;
        off_b = (off_b + bytes + 255) & ~(size_t)255;
        return p;
    };
    float* hidden = (float*)alloc(3 * 128 * 128 * sizeof(float));
    float* hbuf   = (float*)alloc(128 * 128 * sizeof(float));
    float* cbuf   = (float*)alloc(128 * 128 * sizeof(float));
    float* attn   = (float*)alloc(128 * 4 * sizeof(float));
    float* wT     = (float*)alloc(R2C * 128 * sizeof(float));
    float* S      = (float*)alloc(128 * sizeof(float));
    int*   h_set  = (int*)alloc(128 * sizeof(int));
    int*   r_set  = (int*)alloc(128 * sizeof(int));
    int*   invp   = (int*)alloc(128 * sizeof(int));
    int*   t_flat = (int*)alloc(128 * sizeof(int));
    int*   deg    = (int*)alloc(N_ENT * sizeof(int));
    int*   eoff   = (int*)alloc((N_ENT + 1) * sizeof(int));
    int*   cursor = (int*)alloc(N_ENT * sizeof(int));
    int2*  edata  = (int2*)alloc((size_t)E2 * sizeof(int2));
    float* inp    = (float*)alloc((size_t)N_ENT * 128 * sizeof(float));
    float* outs[3];
    for (int i = 0; i < 3; i++) outs[i] = (float*)alloc((size_t)N_ENT * 128 * sizeof(float));

    prep_kernel<<<1, 128, 0, stream>>>(h_index, t_index, r_index, h_set, r_set, invp, t_flat);

    // ---- edge sort by destination (once per launch) ----
    hipMemsetAsync(deg, 0, N_ENT * sizeof(int), stream);
    hipMemsetAsync(cursor, 0, N_ENT * sizeof(int), stream);
    hist_kernel<<<(E2 + 255) / 256, 256, 0, stream>>>(src, dst, deg);
    scan_kernel<<<1, 1024, 0, stream>>>(deg, eoff);
    fill_kernel<<<(E2 + 255) / 256, 256, 0, stream>>>(src, dst, rel, edge_weight,
                                                      eoff, cursor, edata);

    for (int step = 0; step < 3; step++) {
        lstm_step_kernel<<<128, 128, 0, stream>>>(query_emb, r_set, step,
                                                  w_ih, w_hh, b_ih, b_hh,
                                                  hbuf, cbuf, hidden);
    }

    for (int i = 0; i < 3; i++) {
        attn_kernel<<<128, 128, 0, stream>>>(hidden, i, attn);
        relw_kernel<<<128, 256, 0, stream>>>(hidden, i, weight_w, weight_b, wT);
        inp_kernel<<<2048, 128, 0, stream>>>(outs[0], outs[1], i, attn, h_set, inp);
        gather_kernel<<<(N_ENT + 3) / 4, 256, 0, stream>>>(edata, eoff, inp, wT, outs[i]);
        hipMemsetAsync(S, 0, 128 * sizeof(float), stream);
        colsum_kernel<<<256, 128, 0, stream>>>(outs[i], S);
        norm_kernel<<<(N_ENT * 128 + 255) / 256, 256, 0, stream>>>(outs[i], S);
    }

    score_kernel<<<1, 128, 0, stream>>>(outs[2], t_flat, invp, lin_w, lin_b, out);
}

// Round 3
// 323.919 us; speedup vs baseline: 7.0219x; 1.4137x over previous
//
#include <hip/hip_runtime.h>
#include <math.h>

#define N_ENT  15000
#define N_RELC 237
#define R2C    474
#define EBASE  200000
#define E2     400000
#define EPSV   1e-10f

// ---------------------------------------------------------------------------
// Prep: negative_sample_to_tail + rank-based unique + inverse + head ranges.
// Single block, 128 threads. uniq order = ascending (matches jnp.unique),
// padding (fill_value=0) at the end; padded columns are never read by score.
// ---------------------------------------------------------------------------
__global__ void prep_kernel(const int* __restrict__ h_index,
                            const int* __restrict__ t_index,
                            const int* __restrict__ r_index,
                            int* __restrict__ h_set, int* __restrict__ r_set,
                            int* __restrict__ invp, int* __restrict__ t_flat,
                            int* __restrict__ headidx) {
    __shared__ int sv[128];
    __shared__ int eq[128];
    __shared__ int isneg[8];
    __shared__ int f[128];
    __shared__ int uniq[128];
    __shared__ int hsh[128];
    __shared__ int UcntS;
    int j = threadIdx.x;
    int b = j >> 4;
    int h = h_index[j], t = t_index[j], r = r_index[j];

    eq[j] = (h == h_index[b * 16]) ? 1 : 0;
    __syncthreads();
    if ((j & 15) == 0) {
        int a = 1;
        for (int q = 0; q < 16; q++) a &= eq[b * 16 + q];
        isneg[b] = a;
    }
    __syncthreads();

    int hi, ti, ri;
    if (isneg[b]) { hi = h; ti = t; ri = r; }
    else          { hi = t; ti = h; ri = r + N_RELC; }
    t_flat[j] = ti;
    int hrv = hi * R2C + ri;
    sv[j] = hrv;
    uniq[j] = 0;
    __syncthreads();

    // first-occurrence flag
    int first = 1;
    for (int q = 0; q < j; q++) if (sv[q] == hrv) { first = 0; break; }
    f[j] = first;
    __syncthreads();
    // rank = number of distinct values strictly less than mine
    int rank = 0;
    for (int q = 0; q < 128; q++) rank += (f[q] && sv[q] < hrv) ? 1 : 0;
    if (j == 0) {
        int c = 0;
        for (int q = 0; q < 128; q++) c += f[q];
        UcntS = c;
    }
    __syncthreads();
    if (first) uniq[rank] = hrv;
    invp[j] = rank;
    __syncthreads();

    int uv = uniq[j];
    int hs = uv / R2C;
    h_set[j] = hs;
    r_set[j] = uv % R2C;
    hsh[j] = hs;
    __syncthreads();

    // head ranges over real columns [0, Ucnt): sorted by h*R2+r so equal heads
    // are contiguous. headidx[node] = (bstart<<8) | bend, else -1.
    int U = UcntS;
    if (j < U && (j == 0 || hsh[j - 1] != hs)) {
        int e = j + 1;
        while (e < U && hsh[e] == hs) e++;
        headidx[hs] = (j << 8) | e;
    }
}

// ---------------------------------------------------------------------------
// Edge sort by destination: histogram -> scan -> fill.
// ---------------------------------------------------------------------------
__global__ void hist_kernel(const int* __restrict__ src, const int* __restrict__ dst,
                            int* __restrict__ deg) {
    int e = blockIdx.x * 256 + threadIdx.x;
    if (e >= E2) return;
    int no = (e < EBASE) ? dst[e] : src[e - EBASE];
    atomicAdd(&deg[no], 1);
}

__global__ void scan_kernel(const int* __restrict__ deg, int* __restrict__ off) {
    __shared__ int ps[1024];
    int t = threadIdx.x;
    const int CH = 15;
    int base = t * CH;
    int loc = 0;
    for (int q = 0; q < CH; q++) {
        int idx = base + q;
        if (idx < N_ENT) loc += deg[idx];
    }
    ps[t] = loc;
    __syncthreads();
    for (int d = 1; d < 1024; d <<= 1) {
        int v = (t >= d) ? ps[t - d] : 0;
        __syncthreads();
        ps[t] += v;
        __syncthreads();
    }
    int run = ps[t] - loc;
    for (int q = 0; q < CH; q++) {
        int idx = base + q;
        if (idx < N_ENT) { off[idx] = run; run += deg[idx]; }
    }
    if (t == 1023) off[N_ENT] = ps[1023];
}

__global__ void fill_kernel(const int* __restrict__ src, const int* __restrict__ dst,
                            const int* __restrict__ rel, const float* __restrict__ ew,
                            const int* __restrict__ off, int* __restrict__ cursor,
                            int2* __restrict__ edata) {
    int e = blockIdx.x * 256 + threadIdx.x;
    if (e >= E2) return;
    int ni, no, r;
    if (e < EBASE) { ni = src[e]; no = dst[e]; r = rel[e]; }
    else { int e2 = e - EBASE; ni = dst[e2]; no = src[e2]; r = rel[e2] + N_RELC; }
    int pos = off[no] + atomicAdd(&cursor[no], 1);
    edata[pos] = make_int2((ni << 9) | r, __float_as_int(ew[e]));
}

// ---------------------------------------------------------------------------
// Weight transpose for coalesced LSTM reads: wt[d*512+g] = w[g*128+d].
// ---------------------------------------------------------------------------
__global__ void wtrans_kernel(const float* __restrict__ w_ih, const float* __restrict__ w_hh,
                              float* __restrict__ wit, float* __restrict__ wht) {
    int idx = blockIdx.x * 256 + threadIdx.x;
    if (idx >= 512 * 128) return;
    int g = idx >> 7, d = idx & 127;
    wit[d * 512 + g] = w_ih[idx];
    wht[d * 512 + g] = w_hh[idx];
}

// ---------------------------------------------------------------------------
// LSTM, all 3 steps in one kernel. grid=128 (b), block=128 (hidden dim).
// ---------------------------------------------------------------------------
__global__ void lstm_kernel(const float* __restrict__ query_emb,
                            const int* __restrict__ r_set,
                            const float* __restrict__ wit, const float* __restrict__ wht,
                            const float* __restrict__ b_ih, const float* __restrict__ b_hh,
                            float* __restrict__ hidden) {
    int b = blockIdx.x, tid = threadIdx.x;
    __shared__ float x[128], hp[128];
    float bias0 = b_ih[tid]       + b_hh[tid];
    float bias1 = b_ih[128 + tid] + b_hh[128 + tid];
    float bias2 = b_ih[256 + tid] + b_hh[256 + tid];
    float bias3 = b_ih[384 + tid] + b_hh[384 + tid];
    float c = 0.f;
    hp[tid] = 0.f;
    int rs = r_set[b];
    for (int step = 0; step < 3; step++) {
        int qrow = (step < 2) ? rs : R2C;
        x[tid] = query_emb[qrow * 128 + tid];
        __syncthreads();
        float a0 = bias0, a1 = bias1, a2 = bias2, a3 = bias3;
        for (int d = 0; d < 128; d++) {
            float xv = x[d], hv = hp[d];
            const float* wi = wit + d * 512;
            const float* wh = wht + d * 512;
            a0 += xv * wi[tid]       + hv * wh[tid];
            a1 += xv * wi[128 + tid] + hv * wh[128 + tid];
            a2 += xv * wi[256 + tid] + hv * wh[256 + tid];
            a3 += xv * wi[384 + tid] + hv * wh[384 + tid];
        }
        float si = 1.f / (1.f + expf(-a0));
        float sf = 1.f / (1.f + expf(-a1));
        float gg = tanhf(a2);
        float so = 1.f / (1.f + expf(-a3));
        c = sf * c + si * gg;
        float hh = so * tanhf(c);
        __syncthreads();              // everyone done reading hp
        hp[tid] = hh;
        hidden[(step * 128 + b) * 128 + tid] = hh;
    }
}

// ---------------------------------------------------------------------------
// Fused attention + relation softmax + normalization folding.
// attnS[b][t] = attn_t / (t==0 ? 1 : max(S[t-1][b], EPS))
// grid=128 (b), block=256.
// ---------------------------------------------------------------------------
__global__ void coef_kernel(const float* __restrict__ hidden, int step,
                            const float* __restrict__ S,
                            const float* __restrict__ weight_w,
                            const float* __restrict__ weight_b,
                            float* __restrict__ wT, float* __restrict__ attnS) {
    int b = blockIdx.x, tid = threadIdx.x;
    __shared__ float k[128];
    __shared__ float red[256];
    __shared__ float sc[3];
    __shared__ float logit[R2C];
    if (tid < 128) k[tid] = hidden[(step * 128 + b) * 128 + tid];
    __syncthreads();
    for (int t = 0; t <= step; t++) {
        float v = 0.f;
        if (tid < 128) v = k[tid] * hidden[(t * 128 + b) * 128 + tid];
        red[tid] = v;
        __syncthreads();
        for (int s2 = 128; s2 > 0; s2 >>= 1) {
            if (tid < s2) red[tid] += red[tid + s2];
            __syncthreads();
        }
        if (tid == 0) sc[t] = red[0];
        __syncthreads();
    }
    if (tid == 0) {
        float m = sc[0];
        for (int t2 = 1; t2 <= step; t2++) m = fmaxf(m, sc[t2]);
        float ssum = 0.f;
        float ex[3];
        for (int t2 = 0; t2 <= step; t2++) { ex[t2] = expf(sc[t2] - m); ssum += ex[t2]; }
        for (int t2 = 0; t2 <= step; t2++) {
            float a = ex[t2] / ssum;
            if (t2 > 0) a /= fmaxf(S[(t2 - 1) * 128 + b], EPSV);
            attnS[b * 4 + t2] = a;
        }
    }
    // relation softmax
    for (int r = tid; r < R2C; r += 256) {
        const float* wr = weight_w + r * 128;
        float acc = weight_b[r];
        #pragma unroll 8
        for (int d = 0; d < 128; d++) acc += k[d] * wr[d];
        logit[r] = acc;
    }
    __syncthreads();
    float m = -1e30f;
    for (int r = tid; r < R2C; r += 256) m = fmaxf(m, logit[r]);
    red[tid] = m; __syncthreads();
    for (int s2 = 128; s2 > 0; s2 >>= 1) {
        if (tid < s2) red[tid] = fmaxf(red[tid], red[tid + s2]);
        __syncthreads();
    }
    m = red[0]; __syncthreads();
    float s = 0.f;
    for (int r = tid; r < R2C; r += 256) s += expf(logit[r] - m);
    red[tid] = s; __syncthreads();
    for (int s2 = 128; s2 > 0; s2 >>= 1) {
        if (tid < s2) red[tid] += red[tid + s2];
        __syncthreads();
    }
    float invs = 1.f / red[0];
    for (int r = tid; r < R2C; r += 256) wT[r * 128 + b] = expf(logit[r] - m) * invs;
}

// ---------------------------------------------------------------------------
// Step 0: inp = one-hot(h_set) (attn=1), so scatter only edges whose source
// is a head node. out0 must be pre-zeroed.
// ---------------------------------------------------------------------------
__global__ void step0_kernel(const int* __restrict__ src, const int* __restrict__ dst,
                             const int* __restrict__ rel, const float* __restrict__ ew,
                             const int* __restrict__ headidx,
                             const float* __restrict__ wT, float* __restrict__ out0) {
    int e = blockIdx.x * 256 + threadIdx.x;
    if (e >= E2) return;
    int ni, no, r;
    if (e < EBASE) { ni = src[e]; no = dst[e]; r = rel[e]; }
    else { int e2 = e - EBASE; ni = dst[e2]; no = src[e2]; r = rel[e2] + N_RELC; }
    int hv = headidx[ni];
    if (hv < 0) return;
    float w = ew[e];
    int b0 = hv >> 8, b1 = hv & 255;
    for (int b = b0; b < b1; b++)
        atomicAdd(&out0[no * 128 + b], wT[r * 128 + b] * w);
}

// ---------------------------------------------------------------------------
// inp[n][b] = a0*(n==h_set[b]) + a1'*out0[n][b] (+ a2'*out1[n][b])
// ---------------------------------------------------------------------------
__global__ void inp_kernel(const float* __restrict__ o1, const float* __restrict__ o2,
                           int step, const float* __restrict__ attnS,
                           const int* __restrict__ h_set, float* __restrict__ inp) {
    int b = threadIdx.x;
    float a0 = attnS[b * 4 + 0];
    float a1 = attnS[b * 4 + 1];
    float a2 = (step >= 2) ? attnS[b * 4 + 2] : 0.f;
    int hs = h_set[b];
    for (int n = blockIdx.x; n < N_ENT; n += gridDim.x) {
        float v = (n == hs) ? a0 : 0.f;
        v += a1 * o1[n * 128 + b];
        if (step >= 2) v += a2 * o2[n * 128 + b];
        inp[n * 128 + b] = v;
    }
}

// ---------------------------------------------------------------------------
// Gather with 4x unrolled edge loop for MLP. One wave per node, lane = 2 cols.
// ---------------------------------------------------------------------------
__global__ void gather_kernel(const int2* __restrict__ edata,
                              const int* __restrict__ off,
                              const float* __restrict__ inp,
                              const float* __restrict__ wT,
                              float* __restrict__ out) {
    int wid = threadIdx.x >> 6;
    int lane = threadIdx.x & 63;
    int n = blockIdx.x * 4 + wid;
    if (n >= N_ENT) return;
    int e0 = off[n], e1 = off[n + 1];
    int c = lane * 2;
    float ax = 0.f, ay = 0.f;
    int e = e0;
    for (; e + 4 <= e1; e += 4) {
        int2 d0 = edata[e + 0], d1 = edata[e + 1], d2 = edata[e + 2], d3 = edata[e + 3];
        float2 i0 = *(const float2*)(inp + (d0.x >> 9) * 128 + c);
        float2 w0 = *(const float2*)(wT  + (d0.x & 511) * 128 + c);
        float2 i1 = *(const float2*)(inp + (d1.x >> 9) * 128 + c);
        float2 w1 = *(const float2*)(wT  + (d1.x & 511) * 128 + c);
        float2 i2 = *(const float2*)(inp + (d2.x >> 9) * 128 + c);
        float2 w2 = *(const float2*)(wT  + (d2.x & 511) * 128 + c);
        float2 i3 = *(const float2*)(inp + (d3.x >> 9) * 128 + c);
        float2 w3 = *(const float2*)(wT  + (d3.x & 511) * 128 + c);
        float f0 = __int_as_float(d0.y), f1 = __int_as_float(d1.y);
        float f2 = __int_as_float(d2.y), f3 = __int_as_float(d3.y);
        ax += i0.x * w0.x * f0 + i1.x * w1.x * f1 + i2.x * w2.x * f2 + i3.x * w3.x * f3;
        ay += i0.y * w0.y * f0 + i1.y * w1.y * f1 + i2.y * w2.y * f2 + i3.y * w3.y * f3;
    }
    for (; e < e1; e++) {
        int2 ed = edata[e];
        float w = __int_as_float(ed.y);
        float2 a  = *(const float2*)(inp + (ed.x >> 9) * 128 + c);
        float2 ww = *(const float2*)(wT  + (ed.x & 511) * 128 + c);
        ax += a.x * ww.x * w;
        ay += a.y * ww.y * w;
    }
    *(float2*)(out + n * 128 + c) = make_float2(ax, ay);
}

// ---------------------------------------------------------------------------
// Column sums S[b] = sum_n out[n][b]. grid=256, block=128 (thread = b).
// ---------------------------------------------------------------------------
__global__ void colsum_kernel(const float* __restrict__ out, float* __restrict__ S) {
    int b = threadIdx.x;
    float acc = 0.f;
    for (int n = blockIdx.x; n < N_ENT; n += gridDim.x) acc += out[n * 128 + b];
    atomicAdd(&S[b], acc);
}

// score[j] = (out2raw[t_flat[j]][inv[j]] / max(S2, EPS)) * lin_w + lin_b
__global__ void score_kernel(const float* __restrict__ out2raw, const float* __restrict__ S,
                             const int* __restrict__ t_flat, const int* __restrict__ invp,
                             const float* __restrict__ lin_w, const float* __restrict__ lin_b,
                             float* __restrict__ d_out) {
    int j = threadIdx.x;
    int bb = invp[j];
    float s = fmaxf(S[2 * 128 + bb], EPSV);
    d_out[j] = out2raw[t_flat[j] * 128 + bb] / s * lin_w[0] + lin_b[0];
}

// ---------------------------------------------------------------------------
extern "C" void kernel_launch(void* const* d_in, const int* in_sizes, int n_in,
                              void* d_out, int out_size, void* d_ws, size_t ws_size,
                              hipStream_t stream) {
    const float* query_emb  = (const float*)d_in[0];
    const float* w_ih       = (const float*)d_in[1];
    const float* w_hh       = (const float*)d_in[2];
    const float* b_ih       = (const float*)d_in[3];
    const float* b_hh       = (const float*)d_in[4];
    const float* weight_w   = (const float*)d_in[5];
    const float* weight_b   = (const float*)d_in[6];
    const float* lin_w      = (const float*)d_in[7];
    const float* lin_b      = (const float*)d_in[8];
    const float* edge_weight= (const float*)d_in[9];
    const int*   h_index    = (const int*)d_in[10];
    const int*   t_index    = (const int*)d_in[11];
    const int*   r_index    = (const int*)d_in[12];
    const int*   src        = (const int*)d_in[13];
    const int*   dst        = (const int*)d_in[14];
    const int*   rel        = (const int*)d_in[15];
    float* out = (float*)d_out;

    char* ws = (char*)d_ws;
    size_t off_b = 0;
    auto alloc = [&](size_t bytes) -> void* {
        void* p = ws + off_b;
        off_b = (off_b + bytes + 255) & ~(size_t)255;
        return p;
    };
    float* hidden  = (float*)alloc(3 * 128 * 128 * sizeof(float));
    float* attnS   = (float*)alloc(128 * 4 * sizeof(float));
    float* wT      = (float*)alloc(R2C * 128 * sizeof(float));
    float* S       = (float*)alloc(3 * 128 * sizeof(float));
    float* wit     = (float*)alloc(512 * 128 * sizeof(float));
    float* wht     = (float*)alloc(512 * 128 * sizeof(float));
    int*   h_set   = (int*)alloc(128 * sizeof(int));
    int*   r_set   = (int*)alloc(128 * sizeof(int));
    int*   invp    = (int*)alloc(128 * sizeof(int));
    int*   t_flat  = (int*)alloc(128 * sizeof(int));
    int*   degcur  = (int*)alloc(2 * N_ENT * sizeof(int));   // deg | cursor
    int*   eoff    = (int*)alloc((N_ENT + 1) * sizeof(int));
    int*   headidx = (int*)alloc(N_ENT * sizeof(int));
    int2*  edata   = (int2*)alloc((size_t)E2 * sizeof(int2));
    float* inp     = (float*)alloc((size_t)N_ENT * 128 * sizeof(float));
    float* outs[3];
    for (int i = 0; i < 3; i++) outs[i] = (float*)alloc((size_t)N_ENT * 128 * sizeof(float));
    int* deg = degcur;
    int* cursor = degcur + N_ENT;

    hipMemsetAsync(degcur, 0, 2 * N_ENT * sizeof(int), stream);
    hipMemsetAsync(S, 0, 3 * 128 * sizeof(float), stream);
    hipMemsetAsync(headidx, 0xFF, N_ENT * sizeof(int), stream);

    prep_kernel<<<1, 128, 0, stream>>>(h_index, t_index, r_index,
                                       h_set, r_set, invp, t_flat, headidx);

    hist_kernel<<<(E2 + 255) / 256, 256, 0, stream>>>(src, dst, deg);
    scan_kernel<<<1, 1024, 0, stream>>>(deg, eoff);
    fill_kernel<<<(E2 + 255) / 256, 256, 0, stream>>>(src, dst, rel, edge_weight,
                                                      eoff, cursor, edata);

    wtrans_kernel<<<(512 * 128 + 255) / 256, 256, 0, stream>>>(w_ih, w_hh, wit, wht);
    lstm_kernel<<<128, 128, 0, stream>>>(query_emb, r_set, wit, wht, b_ih, b_hh, hidden);

    // ---- step 0: one-hot specialization ----
    coef_kernel<<<128, 256, 0, stream>>>(hidden, 0, S, weight_w, weight_b, wT, attnS);
    hipMemsetAsync(outs[0], 0, (size_t)N_ENT * 128 * sizeof(float), stream);
    step0_kernel<<<(E2 + 255) / 256, 256, 0, stream>>>(src, dst, rel, edge_weight,
                                                       headidx, wT, outs[0]);
    colsum_kernel<<<256, 128, 0, stream>>>(outs[0], S);

    // ---- steps 1, 2: dense gather ----
    for (int i = 1; i < 3; i++) {
        coef_kernel<<<128, 256, 0, stream>>>(hidden, i, S, weight_w, weight_b, wT, attnS);
        inp_kernel<<<2048, 128, 0, stream>>>(outs[0], outs[1], i, attnS, h_set, inp);
        gather_kernel<<<(N_ENT + 3) / 4, 256, 0, stream>>>(edata, eoff, inp, wT, outs[i]);
        colsum_kernel<<<256, 128, 0, stream>>>(outs[i], S + i * 128);
    }

    score_kernel<<<1, 128, 0, stream>>>(outs[2], S, t_flat, invp, lin_w, lin_b, out);
}

// Round 4
// 279.321 us; speedup vs baseline: 8.1430x; 1.1597x over previous
//
#include <hip/hip_runtime.h>
#include <math.h>

#define N_ENT  15000
#define N_RELC 237
#define R2C    474
#define EBASE  200000
#define E2     400000
#define EPSV   1e-10f

typedef unsigned int uint32;
typedef unsigned short ushort16;

__device__ __forceinline__ ushort16 f2bf(float x) {
    uint32 u = __float_as_uint(x);
    u = (u + 0x7FFFu + ((u >> 16) & 1u)) >> 16;   // round-to-nearest-even
    return (ushort16)u;
}
__device__ __forceinline__ float bflo(uint32 u) { return __uint_as_float(u << 16); }
__device__ __forceinline__ float bfhi(uint32 u) { return __uint_as_float(u & 0xFFFF0000u); }

// ---------------------------------------------------------------------------
// init: zero out0 + degcur + Swide, and transpose LSTM weights.
// idx ranges: [0,480000) out0 f4 | 7500 degcur i4 | 768 Swide f4 | 65536 wtrans
// ---------------------------------------------------------------------------
__global__ void init_kernel(float* __restrict__ out0, int* __restrict__ degcur,
                            float* __restrict__ Swide,
                            const float* __restrict__ w_ih, const float* __restrict__ w_hh,
                            float* __restrict__ wit, float* __restrict__ wht) {
    int idx = blockIdx.x * 256 + threadIdx.x;
    float4 z4 = make_float4(0.f, 0.f, 0.f, 0.f);
    if (idx < 480000) { ((float4*)out0)[idx] = z4; return; }
    idx -= 480000;
    if (idx < 7500) { ((int4*)degcur)[idx] = make_int4(0, 0, 0, 0); return; }
    idx -= 7500;
    if (idx < 768) { ((float4*)Swide)[idx] = z4; return; }
    idx -= 768;
    if (idx < 65536) {
        int d = idx >> 9, g = idx & 511;
        wit[idx] = w_ih[g * 128 + d];
        wht[idx] = w_hh[g * 128 + d];
    }
}

// ---------------------------------------------------------------------------
// Prep: negative_sample_to_tail + rank-based unique + inverse + head ranges.
// Single block, 128 threads. Runs AFTER hist_kernel (which inits headidx=-1).
// ---------------------------------------------------------------------------
__global__ void prep_kernel(const int* __restrict__ h_index,
                            const int* __restrict__ t_index,
                            const int* __restrict__ r_index,
                            int* __restrict__ h_set, int* __restrict__ r_set,
                            int* __restrict__ invp, int* __restrict__ t_flat,
                            int* __restrict__ headidx) {
    __shared__ int sv[128];
    __shared__ int eq[128];
    __shared__ int isneg[8];
    __shared__ int f[128];
    __shared__ int uniq[128];
    __shared__ int hsh[128];
    __shared__ int UcntS;
    int j = threadIdx.x;
    int b = j >> 4;
    int h = h_index[j], t = t_index[j], r = r_index[j];

    eq[j] = (h == h_index[b * 16]) ? 1 : 0;
    __syncthreads();
    if ((j & 15) == 0) {
        int a = 1;
        for (int q = 0; q < 16; q++) a &= eq[b * 16 + q];
        isneg[b] = a;
    }
    __syncthreads();

    int hi, ti, ri;
    if (isneg[b]) { hi = h; ti = t; ri = r; }
    else          { hi = t; ti = h; ri = r + N_RELC; }
    t_flat[j] = ti;
    int hrv = hi * R2C + ri;
    sv[j] = hrv;
    uniq[j] = 0;
    __syncthreads();

    int first = 1;
    for (int q = 0; q < j; q++) if (sv[q] == hrv) { first = 0; break; }
    f[j] = first;
    __syncthreads();
    int rank = 0;
    for (int q = 0; q < 128; q++) rank += (f[q] && sv[q] < hrv) ? 1 : 0;
    if (j == 0) {
        int c = 0;
        for (int q = 0; q < 128; q++) c += f[q];
        UcntS = c;
    }
    __syncthreads();
    if (first) uniq[rank] = hrv;
    invp[j] = rank;
    __syncthreads();

    int uv = uniq[j];
    int hs = uv / R2C;
    h_set[j] = hs;
    r_set[j] = uv % R2C;
    hsh[j] = hs;
    __syncthreads();

    int U = UcntS;
    if (j < U && (j == 0 || hsh[j - 1] != hs)) {
        int e = j + 1;
        while (e < U && hsh[e] == hs) e++;
        headidx[hs] = (j << 8) | e;
    }
}

// ---------------------------------------------------------------------------
// Edge histogram by destination + headidx=-1 init (covers N_ENT < E2 range).
// ---------------------------------------------------------------------------
__global__ void hist_kernel(const int* __restrict__ src, const int* __restrict__ dst,
                            int* __restrict__ deg, int* __restrict__ headidx) {
    int e = blockIdx.x * 256 + threadIdx.x;
    if (e < N_ENT) headidx[e] = -1;
    if (e >= E2) return;
    int no = (e < EBASE) ? dst[e] : src[e - EBASE];
    atomicAdd(&deg[no], 1);
}

__global__ void scan_kernel(const int* __restrict__ deg, int* __restrict__ off) {
    __shared__ int ps[1024];
    int t = threadIdx.x;
    const int CH = 15;
    int base = t * CH;
    int loc = 0;
    for (int q = 0; q < CH; q++) {
        int idx = base + q;
        if (idx < N_ENT) loc += deg[idx];
    }
    ps[t] = loc;
    __syncthreads();
    for (int d = 1; d < 1024; d <<= 1) {
        int v = (t >= d) ? ps[t - d] : 0;
        __syncthreads();
        ps[t] += v;
        __syncthreads();
    }
    int run = ps[t] - loc;
    for (int q = 0; q < CH; q++) {
        int idx = base + q;
        if (idx < N_ENT) { off[idx] = run; run += deg[idx]; }
    }
    if (t == 1023) off[N_ENT] = ps[1023];
}

__global__ void fill_kernel(const int* __restrict__ src, const int* __restrict__ dst,
                            const int* __restrict__ rel, const float* __restrict__ ew,
                            const int* __restrict__ off, int* __restrict__ cursor,
                            int2* __restrict__ edata) {
    int e = blockIdx.x * 256 + threadIdx.x;
    if (e >= E2) return;
    int ni, no, r;
    if (e < EBASE) { ni = src[e]; no = dst[e]; r = rel[e]; }
    else { int e2 = e - EBASE; ni = dst[e2]; no = src[e2]; r = rel[e2] + N_RELC; }
    int pos = off[no] + atomicAdd(&cursor[no], 1);
    edata[pos] = make_int2((ni << 9) | r, __float_as_int(ew[e]));
}

// ---------------------------------------------------------------------------
// LSTM, all 3 steps, 2 queries per block. grid=64, block=128.
// ---------------------------------------------------------------------------
__global__ void lstm_kernel(const float* __restrict__ query_emb,
                            const int* __restrict__ r_set,
                            const float* __restrict__ wit, const float* __restrict__ wht,
                            const float* __restrict__ b_ih, const float* __restrict__ b_hh,
                            float* __restrict__ hidden) {
    int b0 = blockIdx.x * 2, tid = threadIdx.x;
    __shared__ float x[2][128], hp[2][128];
    float bias0 = b_ih[tid]       + b_hh[tid];
    float bias1 = b_ih[128 + tid] + b_hh[128 + tid];
    float bias2 = b_ih[256 + tid] + b_hh[256 + tid];
    float bias3 = b_ih[384 + tid] + b_hh[384 + tid];
    float c0 = 0.f, c1 = 0.f;
    hp[0][tid] = 0.f; hp[1][tid] = 0.f;
    int rs0 = r_set[b0], rs1 = r_set[b0 + 1];
    for (int step = 0; step < 3; step++) {
        int q0 = (step < 2) ? rs0 : R2C;
        int q1 = (step < 2) ? rs1 : R2C;
        x[0][tid] = query_emb[q0 * 128 + tid];
        x[1][tid] = query_emb[q1 * 128 + tid];
        __syncthreads();
        float a00 = bias0, a01 = bias1, a02 = bias2, a03 = bias3;
        float a10 = bias0, a11 = bias1, a12 = bias2, a13 = bias3;
        for (int d = 0; d < 128; d++) {
            float xv0 = x[0][d], hv0 = hp[0][d];
            float xv1 = x[1][d], hv1 = hp[1][d];
            const float* wi = wit + d * 512;
            const float* wh = wht + d * 512;
            float wg0 = wi[tid], wg1 = wi[128 + tid], wg2 = wi[256 + tid], wg3 = wi[384 + tid];
            float hg0 = wh[tid], hg1 = wh[128 + tid], hg2 = wh[256 + tid], hg3 = wh[384 + tid];
            a00 += xv0 * wg0 + hv0 * hg0;
            a01 += xv0 * wg1 + hv0 * hg1;
            a02 += xv0 * wg2 + hv0 * hg2;
            a03 += xv0 * wg3 + hv0 * hg3;
            a10 += xv1 * wg0 + hv1 * hg0;
            a11 += xv1 * wg1 + hv1 * hg1;
            a12 += xv1 * wg2 + hv1 * hg2;
            a13 += xv1 * wg3 + hv1 * hg3;
        }
        float si0 = 1.f / (1.f + expf(-a00));
        float sf0 = 1.f / (1.f + expf(-a01));
        float gg0 = tanhf(a02);
        float so0 = 1.f / (1.f + expf(-a03));
        c0 = sf0 * c0 + si0 * gg0;
        float hh0 = so0 * tanhf(c0);
        float si1 = 1.f / (1.f + expf(-a10));
        float sf1 = 1.f / (1.f + expf(-a11));
        float gg1 = tanhf(a12);
        float so1 = 1.f / (1.f + expf(-a13));
        c1 = sf1 * c1 + si1 * gg1;
        float hh1 = so1 * tanhf(c1);
        __syncthreads();
        hp[0][tid] = hh0; hp[1][tid] = hh1;
        hidden[(step * 128 + b0) * 128 + tid] = hh0;
        hidden[(step * 128 + b0 + 1) * 128 + tid] = hh1;
    }
}

// ---------------------------------------------------------------------------
// Fused attention + relation softmax (bf16 out) + normalization folding.
// attnS[b][t] = attn_t / (t==0 ? 1 : max(S[t-1][b], EPS));  S = sum of 8 slices.
// ---------------------------------------------------------------------------
__global__ void coef_kernel(const float* __restrict__ hidden, int step,
                            const float* __restrict__ Swide,
                            const float* __restrict__ weight_w,
                            const float* __restrict__ weight_b,
                            ushort16* __restrict__ wTb, float* __restrict__ attnS) {
    int b = blockIdx.x, tid = threadIdx.x;
    __shared__ float k[128];
    __shared__ float red[256];
    __shared__ float sc[3];
    __shared__ float logit[R2C];
    if (tid < 128) k[tid] = hidden[(step * 128 + b) * 128 + tid];
    __syncthreads();
    for (int t = 0; t <= step; t++) {
        float v = 0.f;
        if (tid < 128) v = k[tid] * hidden[(t * 128 + b) * 128 + tid];
        red[tid] = v;
        __syncthreads();
        for (int s2 = 128; s2 > 0; s2 >>= 1) {
            if (tid < s2) red[tid] += red[tid + s2];
            __syncthreads();
        }
        if (tid == 0) sc[t] = red[0];
        __syncthreads();
    }
    if (tid == 0) {
        float m = sc[0];
        for (int t2 = 1; t2 <= step; t2++) m = fmaxf(m, sc[t2]);
        float ssum = 0.f;
        float ex[3];
        for (int t2 = 0; t2 <= step; t2++) { ex[t2] = expf(sc[t2] - m); ssum += ex[t2]; }
        for (int t2 = 0; t2 <= step; t2++) {
            float a = ex[t2] / ssum;
            if (t2 > 0) {
                float sv = 0.f;
                for (int s8 = 0; s8 < 8; s8++)
                    sv += Swide[(t2 - 1) * 1024 + s8 * 128 + b];
                a /= fmaxf(sv, EPSV);
            }
            attnS[b * 4 + t2] = a;
        }
    }
    for (int r = tid; r < R2C; r += 256) {
        const float* wr = weight_w + r * 128;
        float acc = weight_b[r];
        #pragma unroll 8
        for (int d = 0; d < 128; d++) acc += k[d] * wr[d];
        logit[r] = acc;
    }
    __syncthreads();
    float m = -1e30f;
    for (int r = tid; r < R2C; r += 256) m = fmaxf(m, logit[r]);
    red[tid] = m; __syncthreads();
    for (int s2 = 128; s2 > 0; s2 >>= 1) {
        if (tid < s2) red[tid] = fmaxf(red[tid], red[tid + s2]);
        __syncthreads();
    }
    m = red[0]; __syncthreads();
    float s = 0.f;
    for (int r = tid; r < R2C; r += 256) s += expf(logit[r] - m);
    red[tid] = s; __syncthreads();
    for (int s2 = 128; s2 > 0; s2 >>= 1) {
        if (tid < s2) red[tid] += red[tid + s2];
        __syncthreads();
    }
    float invs = 1.f / red[0];
    for (int r = tid; r < R2C; r += 256)
        wTb[r * 128 + b] = f2bf(expf(logit[r] - m) * invs);
}

// ---------------------------------------------------------------------------
// Step 0: inp = one-hot(h_set); scatter only edges whose source is a head.
// ---------------------------------------------------------------------------
__global__ void step0_kernel(const int* __restrict__ src, const int* __restrict__ dst,
                             const int* __restrict__ rel, const float* __restrict__ ew,
                             const int* __restrict__ headidx,
                             const ushort16* __restrict__ wTb, float* __restrict__ out0) {
    int e = blockIdx.x * 256 + threadIdx.x;
    if (e >= E2) return;
    int ni, no, r;
    if (e < EBASE) { ni = src[e]; no = dst[e]; r = rel[e]; }
    else { int e2 = e - EBASE; ni = dst[e2]; no = src[e2]; r = rel[e2] + N_RELC; }
    int hv = headidx[ni];
    if (hv < 0) return;
    float w = ew[e];
    int b0 = hv >> 8, b1 = hv & 255;
    for (int b = b0; b < b1; b++) {
        float ww = __uint_as_float(((uint32)wTb[r * 128 + b]) << 16);
        atomicAdd(&out0[no * 128 + b], ww * w);
    }
}

// ---------------------------------------------------------------------------
// inp_b16[n][b] = bf16( a0*(n==hs[b]) + a1'*o1[n][b] (+ a2'*o2[n][b]) )
// ---------------------------------------------------------------------------
__global__ void inp_kernel(const float* __restrict__ o1, const float* __restrict__ o2,
                           int step, const float* __restrict__ attnS,
                           const int* __restrict__ h_set, ushort16* __restrict__ inpb) {
    int b = threadIdx.x;
    float a0 = attnS[b * 4 + 0];
    float a1 = attnS[b * 4 + 1];
    float a2 = (step >= 2) ? attnS[b * 4 + 2] : 0.f;
    int hs = h_set[b];
    for (int n = blockIdx.x; n < N_ENT; n += gridDim.x) {
        float v = (n == hs) ? a0 : 0.f;
        v += a1 * o1[n * 128 + b];
        if (step >= 2) v += a2 * o2[n * 128 + b];
        inpb[n * 128 + b] = f2bf(v);
    }
}

// ---------------------------------------------------------------------------
// Gather (bf16 operands, f32 accumulate), 4x unrolled. One wave per node.
// ---------------------------------------------------------------------------
__global__ void gather_kernel(const int2* __restrict__ edata,
                              const int* __restrict__ off,
                              const ushort16* __restrict__ inpb,
                              const ushort16* __restrict__ wTb,
                              float* __restrict__ out) {
    int wid = threadIdx.x >> 6;
    int lane = threadIdx.x & 63;
    int n = blockIdx.x * 4 + wid;
    if (n >= N_ENT) return;
    int e0 = off[n], e1 = off[n + 1];
    int c2 = lane * 2;
    float ax = 0.f, ay = 0.f;
    int e = e0;
    for (; e + 4 <= e1; e += 4) {
        int2 d0 = edata[e + 0], d1 = edata[e + 1], d2 = edata[e + 2], d3 = edata[e + 3];
        uint32 i0 = *(const uint32*)(inpb + ((d0.x >> 9) << 7) + c2);
        uint32 w0 = *(const uint32*)(wTb  + ((d0.x & 511) << 7) + c2);
        uint32 i1 = *(const uint32*)(inpb + ((d1.x >> 9) << 7) + c2);
        uint32 w1 = *(const uint32*)(wTb  + ((d1.x & 511) << 7) + c2);
        uint32 i2 = *(const uint32*)(inpb + ((d2.x >> 9) << 7) + c2);
        uint32 w2 = *(const uint32*)(wTb  + ((d2.x & 511) << 7) + c2);
        uint32 i3 = *(const uint32*)(inpb + ((d3.x >> 9) << 7) + c2);
        uint32 w3 = *(const uint32*)(wTb  + ((d3.x & 511) << 7) + c2);
        float f0 = __int_as_float(d0.y), f1 = __int_as_float(d1.y);
        float f2 = __int_as_float(d2.y), f3 = __int_as_float(d3.y);
        ax += bflo(i0) * bflo(w0) * f0 + bflo(i1) * bflo(w1) * f1
            + bflo(i2) * bflo(w2) * f2 + bflo(i3) * bflo(w3) * f3;
        ay += bfhi(i0) * bfhi(w0) * f0 + bfhi(i1) * bfhi(w1) * f1
            + bfhi(i2) * bfhi(w2) * f2 + bfhi(i3) * bfhi(w3) * f3;
    }
    for (; e < e1; e++) {
        int2 ed = edata[e];
        float w = __int_as_float(ed.y);
        uint32 ia = *(const uint32*)(inpb + ((ed.x >> 9) << 7) + c2);
        uint32 wa = *(const uint32*)(wTb  + ((ed.x & 511) << 7) + c2);
        ax += bflo(ia) * bflo(wa) * w;
        ay += bfhi(ia) * bfhi(wa) * w;
    }
    *(float2*)(out + n * 128 + c2) = make_float2(ax, ay);
}

// ---------------------------------------------------------------------------
// Column sums into 8-slice padded partials: Swide[step][blockIdx&7][b] += acc.
// ---------------------------------------------------------------------------
__global__ void colsum_kernel(const float* __restrict__ out, float* __restrict__ Sslice) {
    int b = threadIdx.x;
    float acc = 0.f;
    for (int n = blockIdx.x; n < N_ENT; n += gridDim.x) acc += out[n * 128 + b];
    atomicAdd(&Sslice[(blockIdx.x & 7) * 128 + b], acc);
}

// score[j] = (out2[t_flat[j]][inv[j]] / max(S2, EPS)) * lin_w + lin_b
__global__ void score_kernel(const float* __restrict__ out2, const float* __restrict__ Swide,
                             const int* __restrict__ t_flat, const int* __restrict__ invp,
                             const float* __restrict__ lin_w, const float* __restrict__ lin_b,
                             float* __restrict__ d_out) {
    int j = threadIdx.x;
    int bb = invp[j];
    float s = 0.f;
    for (int s8 = 0; s8 < 8; s8++) s += Swide[2 * 1024 + s8 * 128 + bb];
    d_out[j] = out2[t_flat[j] * 128 + bb] / fmaxf(s, EPSV) * lin_w[0] + lin_b[0];
}

// ---------------------------------------------------------------------------
extern "C" void kernel_launch(void* const* d_in, const int* in_sizes, int n_in,
                              void* d_out, int out_size, void* d_ws, size_t ws_size,
                              hipStream_t stream) {
    const float* query_emb  = (const float*)d_in[0];
    const float* w_ih       = (const float*)d_in[1];
    const float* w_hh       = (const float*)d_in[2];
    const float* b_ih       = (const float*)d_in[3];
    const float* b_hh       = (const float*)d_in[4];
    const float* weight_w   = (const float*)d_in[5];
    const float* weight_b   = (const float*)d_in[6];
    const float* lin_w      = (const float*)d_in[7];
    const float* lin_b      = (const float*)d_in[8];
    const float* edge_weight= (const float*)d_in[9];
    const int*   h_index    = (const int*)d_in[10];
    const int*   t_index    = (const int*)d_in[11];
    const int*   r_index    = (const int*)d_in[12];
    const int*   src        = (const int*)d_in[13];
    const int*   dst        = (const int*)d_in[14];
    const int*   rel        = (const int*)d_in[15];
    float* out = (float*)d_out;

    char* ws = (char*)d_ws;
    size_t off_b = 0;
    auto alloc = [&](size_t bytes) -> void* {
        void* p = ws + off_b;
        off_b = (off_b + bytes + 255) & ~(size_t)255;
        return p;
    };
    float*    hidden  = (float*)alloc(3 * 128 * 128 * sizeof(float));
    float*    attnS   = (float*)alloc(128 * 4 * sizeof(float));
    ushort16* wTb     = (ushort16*)alloc(R2C * 128 * sizeof(ushort16));
    float*    Swide   = (float*)alloc(3 * 8 * 128 * sizeof(float));
    float*    wit     = (float*)alloc(512 * 128 * sizeof(float));
    float*    wht     = (float*)alloc(512 * 128 * sizeof(float));
    int*      h_set   = (int*)alloc(128 * sizeof(int));
    int*      r_set   = (int*)alloc(128 * sizeof(int));
    int*      invp    = (int*)alloc(128 * sizeof(int));
    int*      t_flat  = (int*)alloc(128 * sizeof(int));
    int*      degcur  = (int*)alloc(2 * N_ENT * sizeof(int));
    int*      eoff    = (int*)alloc((N_ENT + 1) * sizeof(int));
    int*      headidx = (int*)alloc(N_ENT * sizeof(int));
    int2*     edata   = (int2*)alloc((size_t)E2 * sizeof(int2));
    ushort16* inpb    = (ushort16*)alloc((size_t)N_ENT * 128 * sizeof(ushort16));
    float* outs[3];
    for (int i = 0; i < 3; i++) outs[i] = (float*)alloc((size_t)N_ENT * 128 * sizeof(float));
    int* deg = degcur;
    int* cursor = degcur + N_ENT;

    // init: out0 zero, degcur zero, Swide zero, weight transpose
    init_kernel<<<2164, 256, 0, stream>>>(outs[0], degcur, Swide, w_ih, w_hh, wit, wht);
    // hist (also inits headidx = -1)
    hist_kernel<<<(E2 + 255) / 256, 256, 0, stream>>>(src, dst, deg, headidx);
    prep_kernel<<<1, 128, 0, stream>>>(h_index, t_index, r_index,
                                       h_set, r_set, invp, t_flat, headidx);
    scan_kernel<<<1, 1024, 0, stream>>>(deg, eoff);
    fill_kernel<<<(E2 + 255) / 256, 256, 0, stream>>>(src, dst, rel, edge_weight,
                                                      eoff, cursor, edata);

    lstm_kernel<<<64, 128, 0, stream>>>(query_emb, r_set, wit, wht, b_ih, b_hh, hidden);

    // ---- step 0: one-hot specialization ----
    coef_kernel<<<128, 256, 0, stream>>>(hidden, 0, Swide, weight_w, weight_b, wTb, attnS);
    step0_kernel<<<(E2 + 255) / 256, 256, 0, stream>>>(src, dst, rel, edge_weight,
                                                       headidx, wTb, outs[0]);
    colsum_kernel<<<256, 128, 0, stream>>>(outs[0], Swide);

    // ---- steps 1, 2: dense gather ----
    for (int i = 1; i < 3; i++) {
        coef_kernel<<<128, 256, 0, stream>>>(hidden, i, Swide, weight_w, weight_b, wTb, attnS);
        inp_kernel<<<2048, 128, 0, stream>>>(outs[0], outs[1], i, attnS, h_set, inpb);
        gather_kernel<<<(N_ENT + 3) / 4, 256, 0, stream>>>(edata, eoff, inpb, wTb, outs[i]);
        colsum_kernel<<<256, 128, 0, stream>>>(outs[i], Swide + i * 1024);
    }

    score_kernel<<<1, 128, 0, stream>>>(outs[2], Swide, t_flat, invp, lin_w, lin_b, out);
}

// Round 5
// 166.922 us; speedup vs baseline: 13.6262x; 1.6734x over previous
//
#include <hip/hip_runtime.h>
#include <math.h>

#define N_ENT  15000
#define N_RELC 237
#define R2C    474
#define EBASE  200000
#define E2     400000
#define EPSV   1e-10f
#define CAP    72        // per-node edge bucket capacity (Poisson(26.7), P(>=72)~1e-11)
#define NSLICE 64

typedef unsigned int uint32;
typedef unsigned short ushort16;

__device__ __forceinline__ ushort16 f2bf(float x) {
    uint32 u = __float_as_uint(x);
    u = (u + 0x7FFFu + ((u >> 16) & 1u)) >> 16;   // round-to-nearest-even
    return (ushort16)u;
}
__device__ __forceinline__ float bflo(uint32 u) { return __uint_as_float(u << 16); }
__device__ __forceinline__ float bfhi(uint32 u) { return __uint_as_float(u & 0xFFFF0000u); }

// ---------------------------------------------------------------------------
// init: zero out0/cursor/Swide, transpose w_ih/w_hh/weight_w, and (last block)
// run prep: negative_sample_to_tail + rank-based unique + inverse + head ranges.
// idx ranges (256-thr blocks): 480000 out0-f4 | 3750 cursor-i4 | 6144 Swide-f4
//                              | 65536 wit/wht | 65536 wwt
// ---------------------------------------------------------------------------
__global__ void init_kernel(float* __restrict__ out0, int* __restrict__ cursor,
                            float* __restrict__ Swide,
                            const float* __restrict__ w_ih, const float* __restrict__ w_hh,
                            const float* __restrict__ weight_w,
                            float* __restrict__ wit, float* __restrict__ wht,
                            float* __restrict__ wwt,
                            const int* __restrict__ h_index, const int* __restrict__ t_index,
                            const int* __restrict__ r_index,
                            int* __restrict__ h_set, int* __restrict__ r_set,
                            int* __restrict__ invp, int* __restrict__ t_flat,
                            int* __restrict__ headidx) {
    if (blockIdx.x == gridDim.x - 1) {
        // ---- prep block (256 threads, logic on first 128) ----
        __shared__ int sv[128], eq[128], f_[128], uniq[128], hsh[128];
        __shared__ int isneg[8];
        __shared__ int UcntS;
        int j = threadIdx.x;
        for (int idx = j; idx < N_ENT; idx += 256) headidx[idx] = -1;
        __syncthreads();
        int hrv = 0, first = 0, rank = 0;
        if (j < 128) {
            int b = j >> 4;
            int h = h_index[j];
            eq[j] = (h == h_index[b * 16]) ? 1 : 0;
        }
        __syncthreads();
        if (j < 128 && (j & 15) == 0) {
            int b = j >> 4, a = 1;
            for (int q = 0; q < 16; q++) a &= eq[b * 16 + q];
            isneg[b] = a;
        }
        __syncthreads();
        if (j < 128) {
            int b = j >> 4;
            int h = h_index[j], t = t_index[j], r = r_index[j];
            int hi, ti, ri;
            if (isneg[b]) { hi = h; ti = t; ri = r; }
            else          { hi = t; ti = h; ri = r + N_RELC; }
            t_flat[j] = ti;
            hrv = hi * R2C + ri;
            sv[j] = hrv;
            uniq[j] = 0;
        }
        __syncthreads();
        if (j < 128) {
            first = 1;
            for (int q = 0; q < j; q++) if (sv[q] == hrv) { first = 0; break; }
            f_[j] = first;
        }
        __syncthreads();
        if (j < 128) {
            for (int q = 0; q < 128; q++) rank += (f_[q] && sv[q] < hrv) ? 1 : 0;
        }
        if (j == 0) {
            int c = 0;
            for (int q = 0; q < 128; q++) c += f_[q];
            UcntS = c;
        }
        __syncthreads();
        if (j < 128) {
            if (first) uniq[rank] = hrv;
            invp[j] = rank;
        }
        __syncthreads();
        if (j < 128) {
            int uv = uniq[j];
            int hs = uv / R2C;
            h_set[j] = hs;
            r_set[j] = uv % R2C;
            hsh[j] = hs;
        }
        __syncthreads();
        if (j < 128) {
            int U = UcntS;
            int hs = hsh[j];
            if (j < U && (j == 0 || hsh[j - 1] != hs)) {
                int e = j + 1;
                while (e < U && hsh[e] == hs) e++;
                headidx[hs] = (j << 8) | e;
            }
        }
        return;
    }
    int idx = blockIdx.x * 256 + threadIdx.x;
    float4 z4 = make_float4(0.f, 0.f, 0.f, 0.f);
    if (idx < 480000) { ((float4*)out0)[idx] = z4; return; }
    idx -= 480000;
    if (idx < 3750) { ((int4*)cursor)[idx] = make_int4(0, 0, 0, 0); return; }
    idx -= 3750;
    if (idx < 6144) { ((float4*)Swide)[idx] = z4; return; }
    idx -= 6144;
    if (idx < 65536) {
        int d = idx >> 9, g = idx & 511;
        wit[idx] = w_ih[g * 128 + d];
        wht[idx] = w_hh[g * 128 + d];
        return;
    }
    idx -= 65536;
    if (idx < 65536) {
        int d = idx >> 9, r = idx & 511;
        if (r < R2C) wwt[idx] = weight_w[r * 128 + d];
    }
}

// ---------------------------------------------------------------------------
// Bucketed adjacency build: cursor counts degree, edata2[no*CAP + pos].
// ---------------------------------------------------------------------------
__global__ void fill_kernel(const int* __restrict__ src, const int* __restrict__ dst,
                            const int* __restrict__ rel, const float* __restrict__ ew,
                            int* __restrict__ cursor, int2* __restrict__ edata2) {
    int e = blockIdx.x * 256 + threadIdx.x;
    if (e >= E2) return;
    int ni, no, r;
    if (e < EBASE) { ni = src[e]; no = dst[e]; r = rel[e]; }
    else { int e2 = e - EBASE; ni = dst[e2]; no = src[e2]; r = rel[e2] + N_RELC; }
    int pos = atomicAdd(&cursor[no], 1);
    if (pos < CAP)
        edata2[no * CAP + pos] = make_int2((ni << 9) | r, __float_as_int(ew[e]));
}

// ---------------------------------------------------------------------------
// LSTM, all 3 steps. grid=128 (b), block=512 (gate output g).
// x-parts computed in prologue (steps 0,1 share x; step 2 = end token).
// ---------------------------------------------------------------------------
__global__ void lstm_kernel(const float* __restrict__ query_emb,
                            const int* __restrict__ r_set,
                            const float* __restrict__ wit, const float* __restrict__ wht,
                            const float* __restrict__ b_ih, const float* __restrict__ b_hh,
                            float* __restrict__ hidden) {
    int b = blockIdx.x, g = threadIdx.x;
    __shared__ float x[128], h[128], gl[512];
    float bias = b_ih[g] + b_hh[g];
    if (g < 128) x[g] = query_emb[r_set[b] * 128 + g];
    __syncthreads();
    float p0 = 0.f, p1 = 0.f, p2 = 0.f, p3 = 0.f;
    #pragma unroll 8
    for (int d = 0; d < 128; d += 4) {
        p0 += x[d + 0] * wit[(d + 0) * 512 + g];
        p1 += x[d + 1] * wit[(d + 1) * 512 + g];
        p2 += x[d + 2] * wit[(d + 2) * 512 + g];
        p3 += x[d + 3] * wit[(d + 3) * 512 + g];
    }
    float xpA = bias + ((p0 + p1) + (p2 + p3));
    __syncthreads();
    if (g < 128) x[g] = query_emb[R2C * 128 + g];
    __syncthreads();
    p0 = p1 = p2 = p3 = 0.f;
    #pragma unroll 8
    for (int d = 0; d < 128; d += 4) {
        p0 += x[d + 0] * wit[(d + 0) * 512 + g];
        p1 += x[d + 1] * wit[(d + 1) * 512 + g];
        p2 += x[d + 2] * wit[(d + 2) * 512 + g];
        p3 += x[d + 3] * wit[(d + 3) * 512 + g];
    }
    float xpB = bias + ((p0 + p1) + (p2 + p3));
    if (g < 128) h[g] = 0.f;
    float c = 0.f;
    __syncthreads();
    for (int step = 0; step < 3; step++) {
        float a0 = 0.f, a1 = 0.f, a2 = 0.f, a3 = 0.f;
        #pragma unroll 8
        for (int d = 0; d < 128; d += 4) {
            a0 += h[d + 0] * wht[(d + 0) * 512 + g];
            a1 += h[d + 1] * wht[(d + 1) * 512 + g];
            a2 += h[d + 2] * wht[(d + 2) * 512 + g];
            a3 += h[d + 3] * wht[(d + 3) * 512 + g];
        }
        gl[g] = ((step < 2) ? xpA : xpB) + ((a0 + a1) + (a2 + a3));
        __syncthreads();
        if (g < 128) {
            float ig = gl[g], fg = gl[128 + g], gg = gl[256 + g], og = gl[384 + g];
            float si = 1.f / (1.f + expf(-ig));
            float sf = 1.f / (1.f + expf(-fg));
            float so = 1.f / (1.f + expf(-og));
            c = sf * c + si * tanhf(gg);
            float hh = so * tanhf(c);
            hidden[(step * 128 + b) * 128 + g] = hh;
            h[g] = hh;
        }
        __syncthreads();
    }
}

// ---------------------------------------------------------------------------
// Fused attention + relation softmax (bf16 out) + normalization folding.
// attnS[b][t] = attn_t / (t==0 ? 1 : max(S[t-1][b], EPS)); S = sum of slices.
// ---------------------------------------------------------------------------
__global__ void coef_kernel(const float* __restrict__ hidden, int step,
                            const float* __restrict__ Swide,
                            const float* __restrict__ wwt,
                            const float* __restrict__ weight_b,
                            ushort16* __restrict__ wTb, float* __restrict__ attnS) {
    int b = blockIdx.x, tid = threadIdx.x;
    __shared__ float k[128];
    __shared__ float red[256];
    __shared__ float sc[3];
    __shared__ float Ssum[2];
    __shared__ float logit[R2C];
    if (tid < 128) k[tid] = hidden[(step * 128 + b) * 128 + tid];
    __syncthreads();
    for (int t = 0; t <= step; t++) {
        float v = 0.f;
        if (tid < 128) v = k[tid] * hidden[(t * 128 + b) * 128 + tid];
        red[tid] = v;
        __syncthreads();
        for (int s2 = 128; s2 > 0; s2 >>= 1) {
            if (tid < s2) red[tid] += red[tid + s2];
            __syncthreads();
        }
        if (tid == 0) sc[t] = red[0];
        __syncthreads();
    }
    for (int t = 0; t < step; t++) {
        red[tid] = (tid < NSLICE) ? Swide[t * (NSLICE * 128) + tid * 128 + b] : 0.f;
        __syncthreads();
        for (int s2 = 128; s2 > 0; s2 >>= 1) {
            if (tid < s2) red[tid] += red[tid + s2];
            __syncthreads();
        }
        if (tid == 0) Ssum[t] = red[0];
        __syncthreads();
    }
    if (tid == 0) {
        float m = sc[0];
        for (int t2 = 1; t2 <= step; t2++) m = fmaxf(m, sc[t2]);
        float ssum = 0.f;
        float ex[3];
        for (int t2 = 0; t2 <= step; t2++) { ex[t2] = expf(sc[t2] - m); ssum += ex[t2]; }
        for (int t2 = 0; t2 <= step; t2++) {
            float a = ex[t2] / ssum;
            if (t2 > 0) a /= fmaxf(Ssum[t2 - 1], EPSV);
            attnS[b * 4 + t2] = a;
        }
    }
    // relation softmax (coalesced via wwt[d*512+r])
    for (int r = tid; r < R2C; r += 256) {
        float acc = weight_b[r];
        #pragma unroll 8
        for (int d = 0; d < 128; d++) acc += k[d] * wwt[d * 512 + r];
        logit[r] = acc;
    }
    __syncthreads();
    float m = -1e30f;
    for (int r = tid; r < R2C; r += 256) m = fmaxf(m, logit[r]);
    red[tid] = m; __syncthreads();
    for (int s2 = 128; s2 > 0; s2 >>= 1) {
        if (tid < s2) red[tid] = fmaxf(red[tid], red[tid + s2]);
        __syncthreads();
    }
    m = red[0]; __syncthreads();
    float s = 0.f;
    for (int r = tid; r < R2C; r += 256) s += expf(logit[r] - m);
    red[tid] = s; __syncthreads();
    for (int s2 = 128; s2 > 0; s2 >>= 1) {
        if (tid < s2) red[tid] += red[tid + s2];
        __syncthreads();
    }
    float invs = 1.f / red[0];
    for (int r = tid; r < R2C; r += 256)
        wTb[r * 128 + b] = f2bf(expf(logit[r] - m) * invs);
}

// ---------------------------------------------------------------------------
// Step 0: inp = one-hot(h_set); scatter edges whose source is a head node.
// Also accumulates column sums into Swide[0] slices.
// ---------------------------------------------------------------------------
__global__ void step0_kernel(const int* __restrict__ src, const int* __restrict__ dst,
                             const int* __restrict__ rel, const float* __restrict__ ew,
                             const int* __restrict__ headidx,
                             const ushort16* __restrict__ wTb,
                             float* __restrict__ out0, float* __restrict__ Sw0) {
    int e = blockIdx.x * 256 + threadIdx.x;
    if (e >= E2) return;
    int ni, no, r;
    if (e < EBASE) { ni = src[e]; no = dst[e]; r = rel[e]; }
    else { int e2 = e - EBASE; ni = dst[e2]; no = src[e2]; r = rel[e2] + N_RELC; }
    int hv = headidx[ni];
    if (hv < 0) return;
    float w = ew[e];
    int b0 = hv >> 8, b1 = hv & 255;
    int sl = (e & (NSLICE - 1)) * 128;
    for (int b = b0; b < b1; b++) {
        float v = __uint_as_float(((uint32)wTb[r * 128 + b]) << 16) * w;
        atomicAdd(&out0[no * 128 + b], v);
        atomicAdd(&Sw0[sl + b], v);
    }
}

// ---------------------------------------------------------------------------
// inp_b16[n][b] = bf16( a0*(n==hs[b]) + a1'*o1[n][b] (+ a2'*o2[n][b]) )
// ---------------------------------------------------------------------------
__global__ void inp_kernel(const float* __restrict__ o1, const float* __restrict__ o2,
                           int step, const float* __restrict__ attnS,
                           const int* __restrict__ h_set, ushort16* __restrict__ inpb) {
    int b = threadIdx.x;
    float a0 = attnS[b * 4 + 0];
    float a1 = attnS[b * 4 + 1];
    float a2 = (step >= 2) ? attnS[b * 4 + 2] : 0.f;
    int hs = h_set[b];
    for (int n = blockIdx.x; n < N_ENT; n += gridDim.x) {
        float v = (n == hs) ? a0 : 0.f;
        v += a1 * o1[n * 128 + b];
        if (step >= 2) v += a2 * o2[n * 128 + b];
        inpb[n * 128 + b] = f2bf(v);
    }
}

// ---------------------------------------------------------------------------
// Gather (bf16 operands, f32 accumulate) + fused column sums.
// One wave per node (4 nodes / 256-thr block), lane = 2 columns.
// ---------------------------------------------------------------------------
__global__ void gather_kernel(const int2* __restrict__ edata2,
                              const int* __restrict__ cursor,
                              const ushort16* __restrict__ inpb,
                              const ushort16* __restrict__ wTb,
                              float* __restrict__ out, float* __restrict__ Sw) {
    __shared__ float sred[4][128];
    int wid = threadIdx.x >> 6;
    int lane = threadIdx.x & 63;
    int n = blockIdx.x * 4 + wid;                  // grid*4 == N_ENT exactly
    int deg = cursor[n];
    if (deg > CAP) deg = CAP;
    const int2* ed = edata2 + n * CAP;
    int c2 = lane * 2;
    float ax = 0.f, ay = 0.f;
    int e = 0;
    for (; e + 4 <= deg; e += 4) {
        int2 d0 = ed[e + 0], d1 = ed[e + 1], d2 = ed[e + 2], d3 = ed[e + 3];
        uint32 i0 = *(const uint32*)(inpb + ((d0.x >> 9) << 7) + c2);
        uint32 w0 = *(const uint32*)(wTb  + ((d0.x & 511) << 7) + c2);
        uint32 i1 = *(const uint32*)(inpb + ((d1.x >> 9) << 7) + c2);
        uint32 w1 = *(const uint32*)(wTb  + ((d1.x & 511) << 7) + c2);
        uint32 i2 = *(const uint32*)(inpb + ((d2.x >> 9) << 7) + c2);
        uint32 w2 = *(const uint32*)(wTb  + ((d2.x & 511) << 7) + c2);
        uint32 i3 = *(const uint32*)(inpb + ((d3.x >> 9) << 7) + c2);
        uint32 w3 = *(const uint32*)(wTb  + ((d3.x & 511) << 7) + c2);
        float f0 = __int_as_float(d0.y), f1 = __int_as_float(d1.y);
        float f2 = __int_as_float(d2.y), f3 = __int_as_float(d3.y);
        ax += bflo(i0) * bflo(w0) * f0 + bflo(i1) * bflo(w1) * f1
            + bflo(i2) * bflo(w2) * f2 + bflo(i3) * bflo(w3) * f3;
        ay += bfhi(i0) * bfhi(w0) * f0 + bfhi(i1) * bfhi(w1) * f1
            + bfhi(i2) * bfhi(w2) * f2 + bfhi(i3) * bfhi(w3) * f3;
    }
    for (; e < deg; e++) {
        int2 edv = ed[e];
        float w = __int_as_float(edv.y);
        uint32 ia = *(const uint32*)(inpb + ((edv.x >> 9) << 7) + c2);
        uint32 wa = *(const uint32*)(wTb  + ((edv.x & 511) << 7) + c2);
        ax += bflo(ia) * bflo(wa) * w;
        ay += bfhi(ia) * bfhi(wa) * w;
    }
    *(float2*)(out + n * 128 + c2) = make_float2(ax, ay);
    sred[wid][c2] = ax;
    sred[wid][c2 + 1] = ay;
    __syncthreads();
    if (threadIdx.x < 128) {
        float s = sred[0][threadIdx.x] + sred[1][threadIdx.x]
                + sred[2][threadIdx.x] + sred[3][threadIdx.x];
        atomicAdd(&Sw[(blockIdx.x & (NSLICE - 1)) * 128 + threadIdx.x], s);
    }
}

// score[j] = (out2[t_flat[j]][inv[j]] / max(S2, EPS)) * lin_w + lin_b
__global__ void score_kernel(const float* __restrict__ out2, const float* __restrict__ Swide,
                             const int* __restrict__ t_flat, const int* __restrict__ invp,
                             const float* __restrict__ lin_w, const float* __restrict__ lin_b,
                             float* __restrict__ d_out) {
    int j = threadIdx.x;
    int bb = invp[j];
    float s = 0.f;
    for (int s8 = 0; s8 < NSLICE; s8++)
        s += Swide[2 * (NSLICE * 128) + s8 * 128 + bb];
    d_out[j] = out2[t_flat[j] * 128 + bb] / fmaxf(s, EPSV) * lin_w[0] + lin_b[0];
}

// ---------------------------------------------------------------------------
extern "C" void kernel_launch(void* const* d_in, const int* in_sizes, int n_in,
                              void* d_out, int out_size, void* d_ws, size_t ws_size,
                              hipStream_t stream) {
    const float* query_emb  = (const float*)d_in[0];
    const float* w_ih       = (const float*)d_in[1];
    const float* w_hh       = (const float*)d_in[2];
    const float* b_ih       = (const float*)d_in[3];
    const float* b_hh       = (const float*)d_in[4];
    const float* weight_w   = (const float*)d_in[5];
    const float* weight_b   = (const float*)d_in[6];
    const float* lin_w      = (const float*)d_in[7];
    const float* lin_b      = (const float*)d_in[8];
    const float* edge_weight= (const float*)d_in[9];
    const int*   h_index    = (const int*)d_in[10];
    const int*   t_index    = (const int*)d_in[11];
    const int*   r_index    = (const int*)d_in[12];
    const int*   src        = (const int*)d_in[13];
    const int*   dst        = (const int*)d_in[14];
    const int*   rel        = (const int*)d_in[15];
    float* out = (float*)d_out;

    char* ws = (char*)d_ws;
    size_t off_b = 0;
    auto alloc = [&](size_t bytes) -> void* {
        void* p = ws + off_b;
        off_b = (off_b + bytes + 255) & ~(size_t)255;
        return p;
    };
    float*    hidden  = (float*)alloc(3 * 128 * 128 * sizeof(float));
    float*    attnS   = (float*)alloc(128 * 4 * sizeof(float));
    ushort16* wTb     = (ushort16*)alloc(R2C * 128 * sizeof(ushort16));
    float*    Swide   = (float*)alloc(3 * NSLICE * 128 * sizeof(float));
    float*    wit     = (float*)alloc(512 * 128 * sizeof(float));
    float*    wht     = (float*)alloc(512 * 128 * sizeof(float));
    float*    wwt     = (float*)alloc(512 * 128 * sizeof(float));
    int*      h_set   = (int*)alloc(128 * sizeof(int));
    int*      r_set   = (int*)alloc(128 * sizeof(int));
    int*      invp    = (int*)alloc(128 * sizeof(int));
    int*      t_flat  = (int*)alloc(128 * sizeof(int));
    int*      cursor  = (int*)alloc(N_ENT * sizeof(int));
    int*      headidx = (int*)alloc(N_ENT * sizeof(int));
    int2*     edata2  = (int2*)alloc((size_t)N_ENT * CAP * sizeof(int2));
    ushort16* inpb    = (ushort16*)alloc((size_t)N_ENT * 128 * sizeof(ushort16));
    float*    outs0   = (float*)alloc((size_t)N_ENT * 128 * sizeof(float));
    float*    outs1   = (float*)alloc((size_t)N_ENT * 128 * sizeof(float));

    // idx ranges total = 480000+3750+6144+65536+65536 = 620966 -> 2426 blocks + prep
    init_kernel<<<2427, 256, 0, stream>>>(outs0, cursor, Swide, w_ih, w_hh, weight_w,
                                          wit, wht, wwt, h_index, t_index, r_index,
                                          h_set, r_set, invp, t_flat, headidx);
    fill_kernel<<<(E2 + 255) / 256, 256, 0, stream>>>(src, dst, rel, edge_weight,
                                                      cursor, edata2);
    lstm_kernel<<<128, 512, 0, stream>>>(query_emb, r_set, wit, wht, b_ih, b_hh, hidden);

    // ---- step 0: one-hot specialization (col-sums fused into scatter) ----
    coef_kernel<<<128, 256, 0, stream>>>(hidden, 0, Swide, wwt, weight_b, wTb, attnS);
    step0_kernel<<<(E2 + 255) / 256, 256, 0, stream>>>(src, dst, rel, edge_weight,
                                                       headidx, wTb, outs0, Swide);

    // ---- step 1 ----
    coef_kernel<<<128, 256, 0, stream>>>(hidden, 1, Swide, wwt, weight_b, wTb, attnS);
    inp_kernel<<<2048, 128, 0, stream>>>(outs0, outs1, 1, attnS, h_set, inpb);
    gather_kernel<<<N_ENT / 4, 256, 0, stream>>>(edata2, cursor, inpb, wTb,
                                                 outs1, Swide + NSLICE * 128);

    // ---- step 2 (output reuses outs0; inp2 consumed it already) ----
    coef_kernel<<<128, 256, 0, stream>>>(hidden, 2, Swide, wwt, weight_b, wTb, attnS);
    inp_kernel<<<2048, 128, 0, stream>>>(outs0, outs1, 2, attnS, h_set, inpb);
    gather_kernel<<<N_ENT / 4, 256, 0, stream>>>(edata2, cursor, inpb, wTb,
                                                 outs0, Swide + 2 * NSLICE * 128);

    score_kernel<<<1, 128, 0, stream>>>(outs0, Swide, t_flat, invp, lin_w, lin_b, out);
}